// Round 14
// baseline (246.959 us; speedup 1.0000x reference)
//
#include <hip/hip_runtime.h>
#include <hip/hip_bf16.h>

#define NDIM 128
#define NHEAD 8
#define EPSV 1e-5f

#if defined(__has_builtin)
#  if __has_builtin(__builtin_amdgcn_cvt_pk_fp8_f32) && __has_builtin(__builtin_amdgcn_cvt_pk_f32_fp8)
#    define HAVE_FP8 1
#  else
#    define HAVE_FP8 0
#  endif
#else
#  define HAVE_FP8 0
#endif

typedef unsigned short u16;
typedef unsigned char u8;
using bf16x8 = __attribute__((ext_vector_type(8))) short;
using f32x4  = __attribute__((ext_vector_type(4))) float;
using f32x2  = __attribute__((ext_vector_type(2))) float;
using us8    = __attribute__((ext_vector_type(8))) unsigned short;
using us4    = __attribute__((ext_vector_type(4))) unsigned short;

__device__ __forceinline__ u16 f2b(float x){
  union { float f; unsigned u; } v; v.f = x;
  unsigned r = v.u + 0x7FFFu + ((v.u >> 16) & 1u);
  return (u16)(r >> 16);
}
__device__ __forceinline__ float b2f(u16 u){
  union { unsigned u; float f; } v; v.u = ((unsigned)u) << 16; return v.f;
}
__device__ __forceinline__ float blo(unsigned u){
  union { unsigned u; float f; } v; v.u = u << 16; return v.f;
}
__device__ __forceinline__ float bhi(unsigned u){
  union { unsigned u; float f; } v; v.u = u & 0xFFFF0000u; return v.f;
}
__device__ __forceinline__ f32x2 b2f2(unsigned u){
  f32x2 r; r.x = blo(u); r.y = bhi(u); return r;
}

// A-frag: lane provides A[lane%16][(lane/16)*8 + j]; B-frag: B[(lane/16)*8+j][lane%16]
// C/D: col = lane&15, row = (lane>>4)*4 + reg   (measured m89)
template<int NT, int MT, int KS, int WTLD, int XSTR>
__device__ __forceinline__ void gemm_tiles(const u16* X, const u16* __restrict__ WT,
                                           int lr, int kg, int colbase, f32x4 (&acc)[NT][MT]){
  #pragma unroll
  for (int ks = 0; ks < KS; ks++){
    bf16x8 a[MT];
    #pragma unroll
    for (int m = 0; m < MT; m++)
      a[m] = *(const bf16x8*)(X + (size_t)(m*16 + lr)*XSTR + ks*32 + kg*8);
    #pragma unroll
    for (int n = 0; n < NT; n++){
      int col = colbase + n*16 + lr;
      bf16x8 b = *(const bf16x8*)(WT + (size_t)col*WTLD + ks*32 + kg*8);
      #pragma unroll
      for (int m = 0; m < MT; m++)
        acc[n][m] = __builtin_amdgcn_mfma_f32_16x16x32_bf16(a[m], b, acc[n][m], 0, 0, 0);
    }
  }
}

// transpose one 64x64 tile of W (rows x cols, f32) into WT (cols x rows, bf16)
__device__ __forceinline__ void wconv_tile(const float* __restrict__ W, u16* __restrict__ WT,
                                           int rows, int cols, int tr, int tc, int t){
  __shared__ u16 T[64][66];
  int r0 = tr*64, c0 = tc*64;
  int r = t >> 2, cq = (t & 3) * 16;
  const float* src = W + (size_t)(r0 + r)*cols + c0 + cq;
  #pragma unroll
  for (int j = 0; j < 4; j++){
    float4 v = *(const float4*)(src + 4*j);
    us4 o; o.x = f2b(v.x); o.y = f2b(v.y); o.z = f2b(v.z); o.w = f2b(v.w);
    *(us4*)&T[r][cq + 4*j] = o;
  }
  __syncthreads();
  int c = t >> 2, rq = (t & 3) * 16;
  us8 o0, o1;
  #pragma unroll
  for (int j = 0; j < 8; j++){ o0[j] = T[rq + j][c]; o1[j] = T[rq + 8 + j][c]; }
  u16* dstp = WT + (size_t)(c0 + c)*rows + r0 + rq;
  *(us8*)dstp = o0;
  *(us8*)(dstp + 8) = o1;
}

// ============ pro: BN1 stats (nBn) + weight transpose (32) + coarse edge histogram (C chunks) ============
__global__ __launch_bounds__(256) void k_pro(
    const float* __restrict__ Wq, const float* __restrict__ Wk, const float* __restrict__ Wv,
    const float* __restrict__ Wo, const float* __restrict__ W1, const float* __restrict__ W2,
    u16* __restrict__ wtq, u16* __restrict__ wtk, u16* __restrict__ wtv,
    u16* __restrict__ wto, u16* __restrict__ wt1, u16* __restrict__ wt2,
    const float* __restrict__ h, float* __restrict__ sums,
    const int* __restrict__ dst, int* __restrict__ cntT,
    int nBn, int N, int E, int B, int C){
  __shared__ float ls[256], ls2[256];
  __shared__ int hist[256];
  int b = blockIdx.x, t = threadIdx.x;
  if (b < nBn){
    int col = t & 127, half = t >> 7;
    int r0 = b * 128; int r1 = r0 + 128; if (r1 > N) r1 = N;
    float s = 0.f, s2 = 0.f;
    for (int r = r0 + half; r < r1; r += 2){ float v = h[(size_t)r*NDIM + col]; s += v; s2 += v*v; }
    ls[t] = s; ls2[t] = s2; __syncthreads();
    if (t < 128){ atomicAdd(&sums[col], ls[t] + ls[t+128]); atomicAdd(&sums[128+col], ls2[t] + ls2[t+128]); }
    return;
  }
  b -= nBn;
  if (b < 16){
    const float* Ws[4] = {Wq, Wk, Wv, Wo};
    u16* Ts[4] = {wtq, wtk, wtv, wto};
    int wi = b >> 2, ti = b & 3;
    wconv_tile(Ws[wi], Ts[wi], 128, 128, ti >> 1, ti & 1, t);
    return;
  }
  if (b < 24){
    int ti = b - 16;
    wconv_tile(W1, wt1, 128, 256, ti >> 2, ti & 3, t);
    return;
  }
  if (b < 32){
    int ti = b - 24;
    wconv_tile(W2, wt2, 256, 128, ti & 3, ti >> 2, t);
    return;
  }
  int ci = b - 32;
  if (ci >= C) return;
  hist[t] = 0; __syncthreads();
  int e0 = ci * 4096;
  #pragma unroll
  for (int j = 0; j < 16; j++){
    int e = e0 + t + j*256;
    if (e < E) atomicAdd(&hist[dst[e] >> 8], 1);
  }
  __syncthreads();
  if (t < B) cntT[t*C + ci] = hist[t];
}

// ============ standalone BN stats over an fp32 matrix (float4 loads, f32x4 LDS tree) ============
__global__ __launch_bounds__(256) void k_bnstats(const float* __restrict__ x, float* __restrict__ sums, int N){
  __shared__ f32x4 lsS[256], lsQ[256];
  int b = blockIdx.x, t = threadIdx.x;
  int qd = t & 31, rl = t >> 5;
  int r0 = b * 128;
  f32x4 s = {0.f,0.f,0.f,0.f}, sq = {0.f,0.f,0.f,0.f};
  for (int r = rl; r < 128; r += 8){
    int row = r0 + r;
    if (row < N){
      f32x4 v = *(const f32x4*)(x + (size_t)row*NDIM + qd*4);
      s += v; sq += v*v;
    }
  }
  lsS[t] = s; lsQ[t] = sq; __syncthreads();
  if (rl < 4){ lsS[t] += lsS[t+128]; lsQ[t] += lsQ[t+128]; } __syncthreads();
  if (rl < 2){ lsS[t] += lsS[t+64];  lsQ[t] += lsQ[t+64];  } __syncthreads();
  if (rl == 0){
    f32x4 S = lsS[t] + lsS[t+32];
    f32x4 Qv = lsQ[t] + lsQ[t+32];
    atomicAdd(&sums[qd*4+0], S.x); atomicAdd(&sums[qd*4+1], S.y);
    atomicAdd(&sums[qd*4+2], S.z); atomicAdd(&sums[qd*4+3], S.w);
    atomicAdd(&sums[128+qd*4+0], Qv.x); atomicAdd(&sums[128+qd*4+1], Qv.y);
    atomicAdd(&sums[128+qd*4+2], Qv.z); atomicAdd(&sums[128+qd*4+3], Qv.w);
  }
}

// ============ block 0: BN1 finalize; blocks 1..: scan partials over cntT ============
__global__ __launch_bounds__(256) void k_bnf_scan(
    const float* __restrict__ sums, const float* __restrict__ g, const float* __restrict__ b_,
    float* __restrict__ scsh, int N,
    const int* __restrict__ in, int* __restrict__ bsum, int len){
  __shared__ int ls[256];
  int t = threadIdx.x, b = blockIdx.x;
  if (b == 0){
    if (t < 128){
      float mean = sums[t] / (float)N;
      float var  = sums[128+t] / (float)N - mean*mean;
      float rstd = rsqrtf(var + EPSV);
      float sc = g[t] * rstd;
      scsh[t] = sc; scsh[128+t] = b_[t] - mean*sc;
    }
    return;
  }
  b -= 1;
  int i = b*256 + t;
  ls[t] = (i < len) ? in[i] : 0; __syncthreads();
  for (int off = 128; off > 0; off >>= 1){
    if (t < off) ls[t] += ls[t + off];
    __syncthreads();
  }
  if (t == 0) bsum[b] = ls[0];
}

__global__ __launch_bounds__(128) void k_bn_final(const float* __restrict__ sums, const float* __restrict__ g,
                                                  const float* __restrict__ b, float* __restrict__ scsh, int N){
  int c = threadIdx.x;
  float mean = sums[c] / (float)N;
  float var  = sums[128+c] / (float)N - mean*mean;
  float rstd = rsqrtf(var + EPSV);
  float sc = g[c] * rstd;
  scsh[c] = sc; scsh[128+c] = b[c] - mean*sc;
}

__global__ __launch_bounds__(256) void k_scan_top(int* __restrict__ bsum, int nb, int* __restrict__ rowptr, int N, int E){
  __shared__ int ls[256];
  int t = threadIdx.x;
  int v = (t < nb) ? bsum[t] : 0; ls[t] = v; __syncthreads();
  for (int off = 1; off < 256; off <<= 1){
    int add = (t >= off) ? ls[t - off] : 0;
    __syncthreads();
    ls[t] += add;
    __syncthreads();
  }
  if (t < nb) bsum[t] = ls[t] - v;
  if (t == 0) rowptr[N] = E;
}

__global__ __launch_bounds__(256) void k_scan_down(const int* __restrict__ in, const int* __restrict__ bsum,
                                                   int* __restrict__ outp, int len){
  __shared__ int ls[256];
  int t = threadIdx.x; int i = blockIdx.x*256 + t;
  int v = (i < len) ? in[i] : 0; ls[t] = v; __syncthreads();
  for (int off = 1; off < 256; off <<= 1){
    int add = (t >= off) ? ls[t - off] : 0;
    __syncthreads();
    ls[t] += add;
    __syncthreads();
  }
  if (i < len) outp[i] = ls[t] - v + bsum[blockIdx.x];
}

// ============ fine sort within bucket: rowptr + csr_src (LDS atomics only) ============
__global__ __launch_bounds__(256) void k_finesort(const int2* __restrict__ ebuf, const int* __restrict__ scn,
                                                  int* __restrict__ rowptr, int* __restrict__ csr_src,
                                                  int B, int C, int N, int E){
  __shared__ int ls[256], cur[256];
  int b = blockIdx.x, t = threadIdx.x;
  int base = scn[b*C];
  int end  = (b == B-1) ? E : scn[(b+1)*C];
  int lo = b << 8;
  cur[t] = 0; __syncthreads();
  for (int e = base + t; e < end; e += 256) atomicAdd(&cur[ebuf[e].x - lo], 1);
  __syncthreads();
  int v = cur[t]; ls[t] = v; __syncthreads();
  for (int off = 1; off < 256; off <<= 1){
    int add = (t >= off) ? ls[t - off] : 0;
    __syncthreads();
    ls[t] += add;
    __syncthreads();
  }
  int excl = ls[t] - v;
  __syncthreads();
  cur[t] = excl;
  if (lo + t < N) rowptr[lo + t] = base + excl;
  __syncthreads();
  for (int e = base + t; e < end; e += 256){
    int2 p = ebuf[e];
    int slot = base + atomicAdd(&cur[p.x - lo], 1);
    csr_src[slot] = p.y;
  }
}

// ============ merged: bucket pass (first C blocks) + BN1-apply + QKV projection (MFMA, 32-row tiles) ============
// K is emitted as fp8-e4m3 (HAVE_FP8) to halve the sagg K-gather bytes.
__global__ __launch_bounds__(256) void k_qkv_bucket(
    const float* __restrict__ h, const float* __restrict__ scsh,
    const u16* __restrict__ WTq, const u16* __restrict__ WTk, const u16* __restrict__ WTv,
    u16* __restrict__ Q, u16* __restrict__ K, u16* __restrict__ V, int N,
    const int* __restrict__ src, const int* __restrict__ dst,
    const int* __restrict__ scn, int2* __restrict__ ebuf, int B, int C, int E){
  __shared__ u16 hn[32][136];
  __shared__ u16 ob[32][136];
  __shared__ int off[256];
  int b = blockIdx.x, t = threadIdx.x;
  if (b < C){
    off[t] = (t < B) ? scn[t*C + b] : 0;
    __syncthreads();
    int e0 = b * 4096;
    #pragma unroll
    for (int j = 0; j < 16; j++){
      int e = e0 + t + j*256;
      if (e < E){
        int d = dst[e], s = src[e];
        int slot = atomicAdd(&off[d >> 8], 1);
        ebuf[slot] = make_int2(d, s);
      }
    }
    return;
  }
  int r0 = (b - C) * 32;
  int row = t >> 3, c0 = (t & 7) * 16;
  {
    int rr = r0 + row;
    #pragma unroll
    for (int j = 0; j < 4; j++){
      int c = c0 + 4*j;
      float4 v = make_float4(0.f,0.f,0.f,0.f);
      if (rr < N) v = *(const float4*)(h + (size_t)rr*NDIM + c);
      us4 o;
      o.x = f2b(v.x * scsh[c]   + scsh[128+c]);
      o.y = f2b(v.y * scsh[c+1] + scsh[129+c]);
      o.z = f2b(v.z * scsh[c+2] + scsh[130+c]);
      o.w = f2b(v.w * scsh[c+3] + scsh[131+c]);
      *(us4*)&hn[row][c] = o;
    }
  }
  __syncthreads();
  int lane = t & 63, w = t >> 6;
  int lr = lane & 15, kg = lane >> 4;
  f32x4 zero = {0.f,0.f,0.f,0.f};

  #define DO_PASS(WT, OUT, FIRST) { \
    f32x4 acc[2][2]; \
    _Pragma("unroll") for (int n = 0; n < 2; n++) _Pragma("unroll") for (int m = 0; m < 2; m++) acc[n][m] = zero; \
    gemm_tiles<2,2,4,128,136>(&hn[0][0], WT, lr, kg, w*32, acc); \
    if (!FIRST) __syncthreads(); \
    _Pragma("unroll") for (int n = 0; n < 2; n++){ \
      int col = w*32 + n*16 + lr; \
      _Pragma("unroll") for (int m = 0; m < 2; m++) \
        _Pragma("unroll") for (int r = 0; r < 4; r++) \
          ob[m*16 + kg*4 + r][col] = f2b(acc[n][m][r]); \
    } \
    __syncthreads(); \
    if (r0 + row < N){ \
      u16* dp = OUT + (size_t)(r0 + row)*NDIM + c0; \
      *(us8*)dp       = *(const us8*)&ob[row][c0]; \
      *(us8*)(dp + 8) = *(const us8*)&ob[row][c0 + 8]; \
    } }

  DO_PASS(WTq, Q, true)

  // K pass: GEMM -> ob(bf16) -> fp8 (or bf16 fallback) coalesced store
  {
    f32x4 acc[2][2];
    #pragma unroll
    for (int n = 0; n < 2; n++)
      #pragma unroll
      for (int m = 0; m < 2; m++) acc[n][m] = zero;
    gemm_tiles<2,2,4,128,136>(&hn[0][0], WTk, lr, kg, w*32, acc);
    __syncthreads();
    #pragma unroll
    for (int n = 0; n < 2; n++){
      int col = w*32 + n*16 + lr;
      #pragma unroll
      for (int m = 0; m < 2; m++)
        #pragma unroll
        for (int r = 0; r < 4; r++)
          ob[m*16 + kg*4 + r][col] = f2b(acc[n][m][r]);
    }
    __syncthreads();
    if (r0 + row < N){
#if HAVE_FP8
      u8* dp = (u8*)K + (size_t)(r0 + row)*NDIM + c0;
      unsigned wd[4];
      #pragma unroll
      for (int j = 0; j < 2; j++){
        us8 v = *(const us8*)&ob[row][c0 + 8*j];
        int w0 = __builtin_amdgcn_cvt_pk_fp8_f32(b2f(v[0]), b2f(v[1]), 0, false);
        w0     = __builtin_amdgcn_cvt_pk_fp8_f32(b2f(v[2]), b2f(v[3]), w0, true);
        int w1 = __builtin_amdgcn_cvt_pk_fp8_f32(b2f(v[4]), b2f(v[5]), 0, false);
        w1     = __builtin_amdgcn_cvt_pk_fp8_f32(b2f(v[6]), b2f(v[7]), w1, true);
        wd[2*j] = (unsigned)w0; wd[2*j+1] = (unsigned)w1;
      }
      *(uint4*)dp = make_uint4(wd[0], wd[1], wd[2], wd[3]);
#else
      u16* dp = K + (size_t)(r0 + row)*NDIM + c0;
      *(us8*)dp       = *(const us8*)&ob[row][c0];
      *(us8*)(dp + 8) = *(const us8*)&ob[row][c0 + 8];
#endif
    }
  }

  DO_PASS(WTv, V, false)
  #undef DO_PASS
}

// ============ fused edge phase: score + softmax + weighted V aggregation ============
// Depth-2 software pipeline; fp8 K gather (128 B/edge); bf16 V gather (256 B/edge).
__global__ __launch_bounds__(256) void k_sagg(const int* __restrict__ rowptr, const int* __restrict__ csr_src,
                                              const u16* __restrict__ Q, const u16* __restrict__ K,
                                              const u16* __restrict__ V, u16* __restrict__ wV, int N){
  __shared__ float wx[4][64];
  int w = threadIdx.x >> 6, l = threadIdx.x & 63;
  int n = blockIdx.x*4 + w;
  if (n >= N) return;
  int j8 = l >> 3, hh = l & 7, d0 = l * 2;

  f32x2 qf[8];
  {
    const unsigned* qp = (const unsigned*)(Q + (size_t)n*NDIM + hh*16);
    #pragma unroll
    for (int t = 0; t < 8; t++){
      unsigned u = qp[t];
      qf[t].x = blo(u) * 0.25f;
      qf[t].y = bhi(u) * 0.25f;
    }
  }

  int e0 = rowptr[n], e1 = rowptr[n+1];
  int i0 = __builtin_amdgcn_readfirstlane(e0);
  int deg = e1 - e0;
  int nw  = deg >> 3;
  int rem = deg & 7;

  float ssum_l = 0.f;
  f32x2 a01 = {0.f, 0.f};

#if HAVE_FP8
  const u8* Kb = (const u8*)K;
  uint4 kA, kB;
  #define KLOAD(dst_, sidx) dst_ = *(const uint4*)(Kb + (size_t)(sidx)*NDIM + (hh << 4));
  #define KDOTP(p, kk) { \
    f32x2 p2 = {0.f, 0.f}; \
    p2 += qf[0] * __builtin_amdgcn_cvt_pk_f32_fp8((int)kk.x, false); \
    p2 += qf[1] * __builtin_amdgcn_cvt_pk_f32_fp8((int)kk.x, true); \
    p2 += qf[2] * __builtin_amdgcn_cvt_pk_f32_fp8((int)kk.y, false); \
    p2 += qf[3] * __builtin_amdgcn_cvt_pk_f32_fp8((int)kk.y, true); \
    p2 += qf[4] * __builtin_amdgcn_cvt_pk_f32_fp8((int)kk.z, false); \
    p2 += qf[5] * __builtin_amdgcn_cvt_pk_f32_fp8((int)kk.z, true); \
    p2 += qf[6] * __builtin_amdgcn_cvt_pk_f32_fp8((int)kk.w, false); \
    p2 += qf[7] * __builtin_amdgcn_cvt_pk_f32_fp8((int)kk.w, true); \
    p = p2.x + p2.y; }
#else
  struct krow { uint4 lo, hi; };
  krow kA, kB;
  #define KLOAD(dst_, sidx) { \
    const uint4* kp_ = (const uint4*)(K + (size_t)(sidx)*NDIM + hh*16); \
    dst_.lo = kp_[0]; dst_.hi = kp_[1]; }
  #define KDOTP(p, kk) { \
    f32x2 p2 = {0.f, 0.f}; \
    p2 += qf[0] * b2f2(kk.lo.x); p2 += qf[1] * b2f2(kk.lo.y); \
    p2 += qf[2] * b2f2(kk.lo.z); p2 += qf[3] * b2f2(kk.lo.w); \
    p2 += qf[4] * b2f2(kk.hi.x); p2 += qf[5] * b2f2(kk.hi.y); \
    p2 += qf[6] * b2f2(kk.hi.z); p2 += qf[7] * b2f2(kk.hi.w); \
    p = p2.x + p2.y; }
#endif

  unsigned vvA[8], vvB[8];

  if (nw >= 1){
    int s0=csr_src[i0+0], s1=csr_src[i0+1], s2=csr_src[i0+2], s3=csr_src[i0+3];
    int s4=csr_src[i0+4], s5=csr_src[i0+5], s6=csr_src[i0+6], s7=csr_src[i0+7];
    vvA[0] = *(const unsigned*)(V + (size_t)s0*NDIM + d0);
    vvA[1] = *(const unsigned*)(V + (size_t)s1*NDIM + d0);
    vvA[2] = *(const unsigned*)(V + (size_t)s2*NDIM + d0);
    vvA[3] = *(const unsigned*)(V + (size_t)s3*NDIM + d0);
    vvA[4] = *(const unsigned*)(V + (size_t)s4*NDIM + d0);
    vvA[5] = *(const unsigned*)(V + (size_t)s5*NDIM + d0);
    vvA[6] = *(const unsigned*)(V + (size_t)s6*NDIM + d0);
    vvA[7] = *(const unsigned*)(V + (size_t)s7*NDIM + d0);
    int sidx = csr_src[e0 + j8];
    KLOAD(kA, sidx)
  }

  for (int wi = 0; wi < nw; wi++){
    if (wi + 1 < nw){
      int ib = i0 + wi*8 + 8;
      int s0=csr_src[ib+0], s1=csr_src[ib+1], s2=csr_src[ib+2], s3=csr_src[ib+3];
      int s4=csr_src[ib+4], s5=csr_src[ib+5], s6=csr_src[ib+6], s7=csr_src[ib+7];
      vvB[0] = *(const unsigned*)(V + (size_t)s0*NDIM + d0);
      vvB[1] = *(const unsigned*)(V + (size_t)s1*NDIM + d0);
      vvB[2] = *(const unsigned*)(V + (size_t)s2*NDIM + d0);
      vvB[3] = *(const unsigned*)(V + (size_t)s3*NDIM + d0);
      vvB[4] = *(const unsigned*)(V + (size_t)s4*NDIM + d0);
      vvB[5] = *(const unsigned*)(V + (size_t)s5*NDIM + d0);
      vvB[6] = *(const unsigned*)(V + (size_t)s6*NDIM + d0);
      vvB[7] = *(const unsigned*)(V + (size_t)s7*NDIM + d0);
      int sidx = csr_src[e0 + wi*8 + 8 + j8];
      KLOAD(kB, sidx)
    }
    float p;
    KDOTP(p, kA)
    p = fminf(5.f, fmaxf(-5.f, p));
    float wgt = __expf(p);
    ssum_l += wgt;
    wx[w][hh*8 + j8] = wgt;
    float4 wa = *(const float4*)&wx[w][j8*8];
    float4 wb = *(const float4*)&wx[w][j8*8 + 4];
    a01 += b2f2(vvA[0]) * wa.x;
    a01 += b2f2(vvA[1]) * wa.y;
    a01 += b2f2(vvA[2]) * wa.z;
    a01 += b2f2(vvA[3]) * wa.w;
    a01 += b2f2(vvA[4]) * wb.x;
    a01 += b2f2(vvA[5]) * wb.y;
    a01 += b2f2(vvA[6]) * wb.z;
    a01 += b2f2(vvA[7]) * wb.w;
    if (wi + 1 < nw){
      #pragma unroll
      for (int j = 0; j < 8; j++) vvA[j] = vvB[j];
      kA = kB;
    }
  }

  if (rem > 0){
    int i0t = i0 + nw*8;
    int s[8];
    #pragma unroll
    for (int j = 0; j < 8; j++) s[j] = csr_src[i0t + (j < rem ? j : 0)];
    unsigned vv[8];
    #pragma unroll
    for (int j = 0; j < 8; j++) vv[j] = *(const unsigned*)(V + (size_t)s[j]*NDIM + d0);
    int sidx = csr_src[i0t + (j8 < rem ? j8 : 0)];
#if HAVE_FP8
    uint4 kT;
#else
    krow kT;
#endif
    KLOAD(kT, sidx)
    float p;
    KDOTP(p, kT)
    p = fminf(5.f, fmaxf(-5.f, p));
    float wgt = (j8 < rem) ? __expf(p) : 0.f;
    ssum_l += wgt;
    wx[w][hh*8 + j8] = wgt;
    float4 wa = *(const float4*)&wx[w][j8*8];
    float4 wb = *(const float4*)&wx[w][j8*8 + 4];
    a01 += b2f2(vv[0]) * wa.x;
    a01 += b2f2(vv[1]) * wa.y;
    a01 += b2f2(vv[2]) * wa.z;
    a01 += b2f2(vv[3]) * wa.w;
    a01 += b2f2(vv[4]) * wb.x;
    a01 += b2f2(vv[5]) * wb.y;
    a01 += b2f2(vv[6]) * wb.z;
    a01 += b2f2(vv[7]) * wb.w;
  }
  #undef KLOAD
  #undef KDOTP

  ssum_l += __shfl_xor(ssum_l, 8);
  ssum_l += __shfl_xor(ssum_l, 16);
  ssum_l += __shfl_xor(ssum_l, 32);
  float ssum = __shfl(ssum_l, j8);
  float inv = (e1 > e0) ? 1.f/ssum : 0.f;
  unsigned pk = (unsigned)f2b(a01.x*inv) | (((unsigned)f2b(a01.y*inv)) << 16);
  *(unsigned*)(wV + (size_t)n*NDIM + d0) = pk;
}

// ============ O-projection + residual (MFMA, 32-row tiles, coalesced epilogue) ============
__global__ __launch_bounds__(256) void k_h2(const u16* __restrict__ wV, const u16* __restrict__ WTo,
                                            const float* __restrict__ bo, const float* __restrict__ h,
                                            float* __restrict__ h2, int N){
  __shared__ u16 tw[32][136];
  __shared__ float ob[32][132];
  int t = threadIdx.x; int r0 = blockIdx.x * 32;
  int row = t >> 3, c0 = (t & 7) * 16;
  {
    int rr = r0 + row;
    us8 z = {0,0,0,0,0,0,0,0};
    const u16* sp = wV + (size_t)rr*NDIM + c0;
    *(us8*)&tw[row][c0]     = (rr < N) ? *(const us8*)sp       : z;
    *(us8*)&tw[row][c0 + 8] = (rr < N) ? *(const us8*)(sp + 8) : z;
  }
  __syncthreads();
  int lane = t & 63, w = t >> 6;
  int lr = lane & 15, kg = lane >> 4;
  f32x4 zero = {0.f,0.f,0.f,0.f};
  f32x4 acc[2][2];
  #pragma unroll
  for (int n = 0; n < 2; n++)
    #pragma unroll
    for (int m = 0; m < 2; m++) acc[n][m] = zero;
  gemm_tiles<2,2,4,128,136>(&tw[0][0], WTo, lr, kg, w*32, acc);
  #pragma unroll
  for (int n = 0; n < 2; n++){
    int col = w*32 + n*16 + lr;
    float bb = bo[col];
    #pragma unroll
    for (int m = 0; m < 2; m++)
      #pragma unroll
      for (int r = 0; r < 4; r++)
        ob[m*16 + kg*4 + r][col] = acc[n][m][r] + bb;
  }
  __syncthreads();
  if (r0 + row < N){
    const float* hp = h  + (size_t)(r0 + row)*NDIM + c0;
    float*       op = h2 + (size_t)(r0 + row)*NDIM + c0;
    #pragma unroll
    for (int j = 0; j < 4; j++){
      float4 hv = *(const float4*)(hp + 4*j);
      float4 o;
      o.x = ob[row][c0 + 4*j]     + hv.x;
      o.y = ob[row][c0 + 4*j + 1] + hv.y;
      o.z = ob[row][c0 + 4*j + 2] + hv.z;
      o.w = ob[row][c0 + 4*j + 3] + hv.w;
      *(float4*)(op + 4*j) = o;
    }
  }
}

// ============ BN2-apply + FFN + residual (MFMA, 32-row tiles, coalesced epilogue) ============
__global__ __launch_bounds__(256) void k_ffn(const float* __restrict__ h2, const float* __restrict__ scsh,
                                             const u16* __restrict__ WT1, const float* __restrict__ b1,
                                             const u16* __restrict__ WT2, const float* __restrict__ b2,
                                             float* __restrict__ out, int N){
  __shared__ u16 x[32][136];
  __shared__ u16 tt[32][264];          // reused as float [32][132] after GEMM2
  int t = threadIdx.x; int r0 = blockIdx.x * 32;
  int row = t >> 3, c0 = (t & 7) * 16;
  {
    int rr = r0 + row;
    #pragma unroll
    for (int j = 0; j < 4; j++){
      int c = c0 + 4*j;
      float4 v = make_float4(0.f,0.f,0.f,0.f);
      if (rr < N) v = *(const float4*)(h2 + (size_t)rr*NDIM + c);
      us4 o;
      o.x = f2b(v.x * scsh[c]   + scsh[128+c]);
      o.y = f2b(v.y * scsh[c+1] + scsh[129+c]);
      o.z = f2b(v.z * scsh[c+2] + scsh[130+c]);
      o.w = f2b(v.w * scsh[c+3] + scsh[131+c]);
      *(us4*)&x[row][c] = o;
    }
  }
  __syncthreads();
  int lane = t & 63, w = t >> 6;
  int lr = lane & 15, kg = lane >> 4;
  f32x4 zero = {0.f,0.f,0.f,0.f};
  {
    f32x4 a1[4][2];
    #pragma unroll
    for (int n = 0; n < 4; n++)
      #pragma unroll
      for (int m = 0; m < 2; m++) a1[n][m] = zero;
    gemm_tiles<4,2,4,128,136>(&x[0][0], WT1, lr, kg, w*64, a1);
    #pragma unroll
    for (int n = 0; n < 4; n++){
      int col = w*64 + n*16 + lr;
      float bb = b1[col];
      #pragma unroll
      for (int m = 0; m < 2; m++)
        #pragma unroll
        for (int r = 0; r < 4; r++)
          tt[m*16 + kg*4 + r][col] = f2b(fmaxf(a1[n][m][r] + bb, 0.f));
    }
  }
  __syncthreads();
  f32x4 a2[2][2];
  #pragma unroll
  for (int n = 0; n < 2; n++)
    #pragma unroll
    for (int m = 0; m < 2; m++) a2[n][m] = zero;
  gemm_tiles<2,2,8,256,264>(&tt[0][0], WT2, lr, kg, w*32, a2);
  __syncthreads();
  float* ob2 = (float*)&tt[0][0];       // [32][132] overlay
  #pragma unroll
  for (int n = 0; n < 2; n++){
    int col = w*32 + n*16 + lr;
    float bb = b2[col];
    #pragma unroll
    for (int m = 0; m < 2; m++)
      #pragma unroll
      for (int r = 0; r < 4; r++)
        ob2[(m*16 + kg*4 + r)*132 + col] = a2[n][m][r] + bb;
  }
  __syncthreads();
  if (r0 + row < N){
    const float* hp = h2  + (size_t)(r0 + row)*NDIM + c0;
    float*       op = out + (size_t)(r0 + row)*NDIM + c0;
    #pragma unroll
    for (int j = 0; j < 4; j++){
      float4 hv = *(const float4*)(hp + 4*j);
      float4 o;
      o.x = ob2[row*132 + c0 + 4*j]     + hv.x;
      o.y = ob2[row*132 + c0 + 4*j + 1] + hv.y;
      o.z = ob2[row*132 + c0 + 4*j + 2] + hv.z;
      o.w = ob2[row*132 + c0 + 4*j + 3] + hv.w;
      *(float4*)(op + 4*j) = o;
    }
  }
}

extern "C" void kernel_launch(void* const* d_in, const int* in_sizes, int n_in,
                              void* d_out, int out_size, void* d_ws, size_t ws_size,
                              hipStream_t stream) {
  const float* h    = (const float*)d_in[0];
  const int*   src  = (const int*)d_in[1];
  const int*   dst  = (const int*)d_in[2];
  const float* Wq   = (const float*)d_in[3];
  const float* Wk   = (const float*)d_in[4];
  const float* Wv   = (const float*)d_in[5];
  const float* Wo   = (const float*)d_in[6];
  const float* bo   = (const float*)d_in[7];
  const float* bn1g = (const float*)d_in[8];
  const float* bn1b = (const float*)d_in[9];
  const float* bn2g = (const float*)d_in[10];
  const float* bn2b = (const float*)d_in[11];
  const float* W1   = (const float*)d_in[12];
  const float* b1   = (const float*)d_in[13];
  const float* W2   = (const float*)d_in[14];
  const float* b2   = (const float*)d_in[15];
  float* out = (float*)d_out;

  int N = in_sizes[0] / NDIM;
  int E = in_sizes[1];
  size_t fN = (size_t)N * NDIM;

  int B   = (N + 255) >> 8;       // coarse buckets (256 nodes each), <= 256
  int C   = (E + 4095) >> 12;     // edge chunks (4096 edges each)
  int NB2 = B * C;
  int nb2 = (NB2 + 255) / 256;    // <= 256

  u16* Q  = (u16*)d_ws;
  u16* K  = Q + fN;               // fp8 path uses first fN BYTES of this 2*fN-byte slot
  u16* V  = K + fN;
  u16* wV = Q;                    // reuse: each wave reads Q[n] before writing wV[n]
  float* h2   = (float*)(V + fN);
  int2* ebuf  = (int2*)(h2 + fN);
  int* rowptr = (int*)(ebuf + E);
  int* bsum   = rowptr + (N + 1);
  int* cntT   = bsum + 256;
  int* scn    = cntT + NB2;
  int* csr_src= scn + NB2;
  float* sums1 = (float*)(csr_src + E);
  float* sums2 = sums1 + 256;
  float* scsh1 = sums2 + 256;
  float* scsh2 = scsh1 + 256;
  u16* wtq = (u16*)(scsh2 + 256);
  u16* wtk = wtq + NDIM*NDIM;
  u16* wtv = wtk + NDIM*NDIM;
  u16* wto = wtv + NDIM*NDIM;
  u16* wt1 = wto + NDIM*NDIM;
  u16* wt2 = wt1 + NDIM*2*NDIM;

  hipMemsetAsync(sums1, 0, 512 * sizeof(float), stream);   // sums1 + sums2

  int nBn = (N + 127) / 128;
  int n32 = (N + 31) / 32;

  k_pro<<<nBn + 32 + C, 256, 0, stream>>>(Wq, Wk, Wv, Wo, W1, W2,
                                          wtq, wtk, wtv, wto, wt1, wt2,
                                          h, sums1, dst, cntT, nBn, N, E, B, C);
  k_bnf_scan<<<1 + nb2, 256, 0, stream>>>(sums1, bn1g, bn1b, scsh1, N, cntT, bsum, NB2);
  k_scan_top<<<1, 256, 0, stream>>>(bsum, nb2, rowptr, N, E);
  k_scan_down<<<nb2, 256, 0, stream>>>(cntT, bsum, scn, NB2);

  k_qkv_bucket<<<C + n32, 256, 0, stream>>>(h, scsh1, wtq, wtk, wtv, Q, K, V, N,
                                            src, dst, scn, ebuf, B, C, E);
  k_finesort<<<B, 256, 0, stream>>>(ebuf, scn, rowptr, csr_src, B, C, N, E);

  k_sagg<<<(N + 3)/4, 256, 0, stream>>>(rowptr, csr_src, Q, K, V, wV, N);

  k_h2<<<n32, 256, 0, stream>>>(wV, wto, bo, h, h2, N);
  k_bnstats<<<nBn, 256, 0, stream>>>(h2, sums2, N);
  k_bn_final<<<1, 128, 0, stream>>>(sums2, bn2g, bn2b, scsh2, N);
  k_ffn<<<n32, 256, 0, stream>>>(h2, scsh2, wt1, b1, wt2, b2, out, N);
}

// Round 15
// 241.424 us; speedup vs baseline: 1.0229x; 1.0229x over previous
//
#include <hip/hip_runtime.h>
#include <hip/hip_bf16.h>

#define NDIM 128
#define NHEAD 8
#define EPSV 1e-5f

#if defined(__has_builtin)
#  if __has_builtin(__builtin_amdgcn_cvt_pk_fp8_f32) && __has_builtin(__builtin_amdgcn_cvt_pk_f32_fp8)
#    define HAVE_FP8 1
#  else
#    define HAVE_FP8 0
#  endif
#else
#  define HAVE_FP8 0
#endif

typedef unsigned short u16;
typedef unsigned char u8;
using bf16x8 = __attribute__((ext_vector_type(8))) short;
using f32x4  = __attribute__((ext_vector_type(4))) float;
using f32x2  = __attribute__((ext_vector_type(2))) float;
using us8    = __attribute__((ext_vector_type(8))) unsigned short;
using us4    = __attribute__((ext_vector_type(4))) unsigned short;

__device__ __forceinline__ u16 f2b(float x){
  union { float f; unsigned u; } v; v.f = x;
  unsigned r = v.u + 0x7FFFu + ((v.u >> 16) & 1u);
  return (u16)(r >> 16);
}
__device__ __forceinline__ float b2f(u16 u){
  union { unsigned u; float f; } v; v.u = ((unsigned)u) << 16; return v.f;
}
__device__ __forceinline__ float blo(unsigned u){
  union { unsigned u; float f; } v; v.u = u << 16; return v.f;
}
__device__ __forceinline__ float bhi(unsigned u){
  union { unsigned u; float f; } v; v.u = u & 0xFFFF0000u; return v.f;
}
__device__ __forceinline__ f32x2 b2f2(unsigned u){
  f32x2 r; r.x = blo(u); r.y = bhi(u); return r;
}

// A-frag: lane provides A[lane%16][(lane/16)*8 + j]; B-frag: B[(lane/16)*8+j][lane%16]
// C/D: col = lane&15, row = (lane>>4)*4 + reg   (measured m89)
template<int NT, int MT, int KS, int WTLD, int XSTR>
__device__ __forceinline__ void gemm_tiles(const u16* X, const u16* __restrict__ WT,
                                           int lr, int kg, int colbase, f32x4 (&acc)[NT][MT]){
  #pragma unroll
  for (int ks = 0; ks < KS; ks++){
    bf16x8 a[MT];
    #pragma unroll
    for (int m = 0; m < MT; m++)
      a[m] = *(const bf16x8*)(X + (size_t)(m*16 + lr)*XSTR + ks*32 + kg*8);
    #pragma unroll
    for (int n = 0; n < NT; n++){
      int col = colbase + n*16 + lr;
      bf16x8 b = *(const bf16x8*)(WT + (size_t)col*WTLD + ks*32 + kg*8);
      #pragma unroll
      for (int m = 0; m < MT; m++)
        acc[n][m] = __builtin_amdgcn_mfma_f32_16x16x32_bf16(a[m], b, acc[n][m], 0, 0, 0);
    }
  }
}

// transpose one 64x64 tile of W (rows x cols, f32) into WT (cols x rows, bf16)
__device__ __forceinline__ void wconv_tile(const float* __restrict__ W, u16* __restrict__ WT,
                                           int rows, int cols, int tr, int tc, int t){
  __shared__ u16 T[64][66];
  int r0 = tr*64, c0 = tc*64;
  int r = t >> 2, cq = (t & 3) * 16;
  const float* src = W + (size_t)(r0 + r)*cols + c0 + cq;
  #pragma unroll
  for (int j = 0; j < 4; j++){
    float4 v = *(const float4*)(src + 4*j);
    us4 o; o.x = f2b(v.x); o.y = f2b(v.y); o.z = f2b(v.z); o.w = f2b(v.w);
    *(us4*)&T[r][cq + 4*j] = o;
  }
  __syncthreads();
  int c = t >> 2, rq = (t & 3) * 16;
  us8 o0, o1;
  #pragma unroll
  for (int j = 0; j < 8; j++){ o0[j] = T[rq + j][c]; o1[j] = T[rq + 8 + j][c]; }
  u16* dstp = WT + (size_t)(c0 + c)*rows + r0 + rq;
  *(us8*)dstp = o0;
  *(us8*)(dstp + 8) = o1;
}

// ============ pro: BN1 partials (nBn) + weight transpose (32) + coarse edge histogram (C chunks) ============
// BN1 partials: per-block column sums -> part1[b][256] (NO global atomics).
__global__ __launch_bounds__(256) void k_pro(
    const float* __restrict__ Wq, const float* __restrict__ Wk, const float* __restrict__ Wv,
    const float* __restrict__ Wo, const float* __restrict__ W1, const float* __restrict__ W2,
    u16* __restrict__ wtq, u16* __restrict__ wtk, u16* __restrict__ wtv,
    u16* __restrict__ wto, u16* __restrict__ wt1, u16* __restrict__ wt2,
    const float* __restrict__ h, float* __restrict__ part1,
    const int* __restrict__ dst, int* __restrict__ cntT,
    int nBn, int N, int E, int B, int C){
  __shared__ float ls[256], ls2[256];
  __shared__ int hist[256];
  int b = blockIdx.x, t = threadIdx.x;
  if (b < nBn){
    int col = t & 127, half = t >> 7;
    int r0 = b * 128; int r1 = r0 + 128; if (r1 > N) r1 = N;
    float s = 0.f, s2 = 0.f;
    for (int r = r0 + half; r < r1; r += 2){ float v = h[(size_t)r*NDIM + col]; s += v; s2 += v*v; }
    ls[t] = s; ls2[t] = s2; __syncthreads();
    if (t < 128){
      part1[(size_t)b*256 + t]       = ls[t] + ls[t+128];
      part1[(size_t)b*256 + 128 + t] = ls2[t] + ls2[t+128];
    }
    return;
  }
  b -= nBn;
  if (b < 16){
    const float* Ws[4] = {Wq, Wk, Wv, Wo};
    u16* Ts[4] = {wtq, wtk, wtv, wto};
    int wi = b >> 2, ti = b & 3;
    wconv_tile(Ws[wi], Ts[wi], 128, 128, ti >> 1, ti & 1, t);
    return;
  }
  if (b < 24){
    int ti = b - 16;
    wconv_tile(W1, wt1, 128, 256, ti >> 2, ti & 3, t);
    return;
  }
  if (b < 32){
    int ti = b - 24;
    wconv_tile(W2, wt2, 256, 128, ti & 3, ti >> 2, t);
    return;
  }
  int ci = b - 32;
  if (ci >= C) return;
  hist[t] = 0; __syncthreads();
  int e0 = ci * 4096;
  #pragma unroll
  for (int j = 0; j < 16; j++){
    int e = e0 + t + j*256;
    if (e < E) atomicAdd(&hist[dst[e] >> 8], 1);
  }
  __syncthreads();
  if (t < B) cntT[t*C + ci] = hist[t];
}

// ============ BN2 partials over h2 (float4 loads, NO global atomics) ============
__global__ __launch_bounds__(256) void k_bnstats(const float* __restrict__ x, float* __restrict__ part, int N){
  __shared__ f32x4 lsS[256], lsQ[256];
  int b = blockIdx.x, t = threadIdx.x;
  int qd = t & 31, rl = t >> 5;
  int r0 = b * 128;
  f32x4 s = {0.f,0.f,0.f,0.f}, sq = {0.f,0.f,0.f,0.f};
  for (int r = rl; r < 128; r += 8){
    int row = r0 + r;
    if (row < N){
      f32x4 v = *(const f32x4*)(x + (size_t)row*NDIM + qd*4);
      s += v; sq += v*v;
    }
  }
  lsS[t] = s; lsQ[t] = sq; __syncthreads();
  if (rl < 4){ lsS[t] += lsS[t+128]; lsQ[t] += lsQ[t+128]; } __syncthreads();
  if (rl < 2){ lsS[t] += lsS[t+64];  lsQ[t] += lsQ[t+64];  } __syncthreads();
  if (rl == 0){
    f32x4 S  = lsS[t] + lsS[t+32];
    f32x4 Qv = lsQ[t] + lsQ[t+32];
    *(f32x4*)&part[(size_t)b*256 + qd*4]       = S;
    *(f32x4*)&part[(size_t)b*256 + 128 + qd*4] = Qv;
  }
}

// deterministic partials reduce: acc[t] = sum_i part[i*256 + t]
__device__ __forceinline__ float reduce_part(const float* __restrict__ part, int nBn, int t){
  float a0 = 0.f, a1 = 0.f, a2 = 0.f, a3 = 0.f;
  int i = 0;
  for (; i + 4 <= nBn; i += 4){
    a0 += part[(size_t)(i+0)*256 + t];
    a1 += part[(size_t)(i+1)*256 + t];
    a2 += part[(size_t)(i+2)*256 + t];
    a3 += part[(size_t)(i+3)*256 + t];
  }
  for (; i < nBn; i++) a0 += part[(size_t)i*256 + t];
  return (a0 + a1) + (a2 + a3);
}

// ============ block 0: BN1 reduce+finalize; blocks 1..: scan partials over cntT ============
__global__ __launch_bounds__(256) void k_bnf_scan(
    const float* __restrict__ part1, int nBn,
    const float* __restrict__ g, const float* __restrict__ b_,
    float* __restrict__ scsh, int N,
    const int* __restrict__ in, int* __restrict__ bsum, int len){
  __shared__ int ls[256];
  __shared__ float sm[256];
  int t = threadIdx.x, b = blockIdx.x;
  if (b == 0){
    sm[t] = reduce_part(part1, nBn, t);
    __syncthreads();
    if (t < 128){
      float mean = sm[t] / (float)N;
      float var  = sm[128+t] / (float)N - mean*mean;
      float rstd = rsqrtf(var + EPSV);
      float sc = g[t] * rstd;
      scsh[t] = sc; scsh[128+t] = b_[t] - mean*sc;
    }
    return;
  }
  b -= 1;
  int i = b*256 + t;
  ls[t] = (i < len) ? in[i] : 0; __syncthreads();
  for (int off = 128; off > 0; off >>= 1){
    if (t < off) ls[t] += ls[t + off];
    __syncthreads();
  }
  if (t == 0) bsum[b] = ls[0];
}

// ============ BN2 reduce + finalize ============
__global__ __launch_bounds__(256) void k_bn_final(const float* __restrict__ part, int nBn,
                                                  const float* __restrict__ g, const float* __restrict__ b,
                                                  float* __restrict__ scsh, int N){
  __shared__ float sm[256];
  int t = threadIdx.x;
  sm[t] = reduce_part(part, nBn, t);
  __syncthreads();
  if (t < 128){
    float mean = sm[t] / (float)N;
    float var  = sm[128+t] / (float)N - mean*mean;
    float rstd = rsqrtf(var + EPSV);
    float sc = g[t] * rstd;
    scsh[t] = sc; scsh[128+t] = b[t] - mean*sc;
  }
}

__global__ __launch_bounds__(256) void k_scan_top(int* __restrict__ bsum, int nb, int* __restrict__ rowptr, int N, int E){
  __shared__ int ls[256];
  int t = threadIdx.x;
  int v = (t < nb) ? bsum[t] : 0; ls[t] = v; __syncthreads();
  for (int off = 1; off < 256; off <<= 1){
    int add = (t >= off) ? ls[t - off] : 0;
    __syncthreads();
    ls[t] += add;
    __syncthreads();
  }
  if (t < nb) bsum[t] = ls[t] - v;
  if (t == 0) rowptr[N] = E;
}

__global__ __launch_bounds__(256) void k_scan_down(const int* __restrict__ in, const int* __restrict__ bsum,
                                                   int* __restrict__ outp, int len){
  __shared__ int ls[256];
  int t = threadIdx.x; int i = blockIdx.x*256 + t;
  int v = (i < len) ? in[i] : 0; ls[t] = v; __syncthreads();
  for (int off = 1; off < 256; off <<= 1){
    int add = (t >= off) ? ls[t - off] : 0;
    __syncthreads();
    ls[t] += add;
    __syncthreads();
  }
  if (i < len) outp[i] = ls[t] - v + bsum[blockIdx.x];
}

// ============ fine sort within bucket: rowptr + csr_src (LDS atomics only) ============
__global__ __launch_bounds__(256) void k_finesort(const int2* __restrict__ ebuf, const int* __restrict__ scn,
                                                  int* __restrict__ rowptr, int* __restrict__ csr_src,
                                                  int B, int C, int N, int E){
  __shared__ int ls[256], cur[256];
  int b = blockIdx.x, t = threadIdx.x;
  int base = scn[b*C];
  int end  = (b == B-1) ? E : scn[(b+1)*C];
  int lo = b << 8;
  cur[t] = 0; __syncthreads();
  for (int e = base + t; e < end; e += 256) atomicAdd(&cur[ebuf[e].x - lo], 1);
  __syncthreads();
  int v = cur[t]; ls[t] = v; __syncthreads();
  for (int off = 1; off < 256; off <<= 1){
    int add = (t >= off) ? ls[t - off] : 0;
    __syncthreads();
    ls[t] += add;
    __syncthreads();
  }
  int excl = ls[t] - v;
  __syncthreads();
  cur[t] = excl;
  if (lo + t < N) rowptr[lo + t] = base + excl;
  __syncthreads();
  for (int e = base + t; e < end; e += 256){
    int2 p = ebuf[e];
    int slot = base + atomicAdd(&cur[p.x - lo], 1);
    csr_src[slot] = p.y;
  }
}

// ============ merged: bucket pass (first C blocks) + BN1-apply + QKV projection (MFMA, 32-row tiles) ============
// K is emitted as fp8-e4m3 (HAVE_FP8) to halve the sagg K-gather bytes.
__global__ __launch_bounds__(256) void k_qkv_bucket(
    const float* __restrict__ h, const float* __restrict__ scsh,
    const u16* __restrict__ WTq, const u16* __restrict__ WTk, const u16* __restrict__ WTv,
    u16* __restrict__ Q, u16* __restrict__ K, u16* __restrict__ V, int N,
    const int* __restrict__ src, const int* __restrict__ dst,
    const int* __restrict__ scn, int2* __restrict__ ebuf, int B, int C, int E){
  __shared__ u16 hn[32][136];
  __shared__ u16 ob[32][136];
  __shared__ int off[256];
  int b = blockIdx.x, t = threadIdx.x;
  if (b < C){
    off[t] = (t < B) ? scn[t*C + b] : 0;
    __syncthreads();
    int e0 = b * 4096;
    #pragma unroll
    for (int j = 0; j < 16; j++){
      int e = e0 + t + j*256;
      if (e < E){
        int d = dst[e], s = src[e];
        int slot = atomicAdd(&off[d >> 8], 1);
        ebuf[slot] = make_int2(d, s);
      }
    }
    return;
  }
  int r0 = (b - C) * 32;
  int row = t >> 3, c0 = (t & 7) * 16;
  {
    int rr = r0 + row;
    #pragma unroll
    for (int j = 0; j < 4; j++){
      int c = c0 + 4*j;
      float4 v = make_float4(0.f,0.f,0.f,0.f);
      if (rr < N) v = *(const float4*)(h + (size_t)rr*NDIM + c);
      us4 o;
      o.x = f2b(v.x * scsh[c]   + scsh[128+c]);
      o.y = f2b(v.y * scsh[c+1] + scsh[129+c]);
      o.z = f2b(v.z * scsh[c+2] + scsh[130+c]);
      o.w = f2b(v.w * scsh[c+3] + scsh[131+c]);
      *(us4*)&hn[row][c] = o;
    }
  }
  __syncthreads();
  int lane = t & 63, w = t >> 6;
  int lr = lane & 15, kg = lane >> 4;
  f32x4 zero = {0.f,0.f,0.f,0.f};

  #define DO_PASS(WT, OUT, FIRST) { \
    f32x4 acc[2][2]; \
    _Pragma("unroll") for (int n = 0; n < 2; n++) _Pragma("unroll") for (int m = 0; m < 2; m++) acc[n][m] = zero; \
    gemm_tiles<2,2,4,128,136>(&hn[0][0], WT, lr, kg, w*32, acc); \
    if (!FIRST) __syncthreads(); \
    _Pragma("unroll") for (int n = 0; n < 2; n++){ \
      int col = w*32 + n*16 + lr; \
      _Pragma("unroll") for (int m = 0; m < 2; m++) \
        _Pragma("unroll") for (int r = 0; r < 4; r++) \
          ob[m*16 + kg*4 + r][col] = f2b(acc[n][m][r]); \
    } \
    __syncthreads(); \
    if (r0 + row < N){ \
      u16* dp = OUT + (size_t)(r0 + row)*NDIM + c0; \
      *(us8*)dp       = *(const us8*)&ob[row][c0]; \
      *(us8*)(dp + 8) = *(const us8*)&ob[row][c0 + 8]; \
    } }

  DO_PASS(WTq, Q, true)

  // K pass: GEMM -> ob(bf16) -> fp8 (or bf16 fallback) coalesced store
  {
    f32x4 acc[2][2];
    #pragma unroll
    for (int n = 0; n < 2; n++)
      #pragma unroll
      for (int m = 0; m < 2; m++) acc[n][m] = zero;
    gemm_tiles<2,2,4,128,136>(&hn[0][0], WTk, lr, kg, w*32, acc);
    __syncthreads();
    #pragma unroll
    for (int n = 0; n < 2; n++){
      int col = w*32 + n*16 + lr;
      #pragma unroll
      for (int m = 0; m < 2; m++)
        #pragma unroll
        for (int r = 0; r < 4; r++)
          ob[m*16 + kg*4 + r][col] = f2b(acc[n][m][r]);
    }
    __syncthreads();
    if (r0 + row < N){
#if HAVE_FP8
      u8* dp = (u8*)K + (size_t)(r0 + row)*NDIM + c0;
      unsigned wd[4];
      #pragma unroll
      for (int j = 0; j < 2; j++){
        us8 v = *(const us8*)&ob[row][c0 + 8*j];
        int w0 = __builtin_amdgcn_cvt_pk_fp8_f32(b2f(v[0]), b2f(v[1]), 0, false);
        w0     = __builtin_amdgcn_cvt_pk_fp8_f32(b2f(v[2]), b2f(v[3]), w0, true);
        int w1 = __builtin_amdgcn_cvt_pk_fp8_f32(b2f(v[4]), b2f(v[5]), 0, false);
        w1     = __builtin_amdgcn_cvt_pk_fp8_f32(b2f(v[6]), b2f(v[7]), w1, true);
        wd[2*j] = (unsigned)w0; wd[2*j+1] = (unsigned)w1;
      }
      *(uint4*)dp = make_uint4(wd[0], wd[1], wd[2], wd[3]);
#else
      u16* dp = K + (size_t)(r0 + row)*NDIM + c0;
      *(us8*)dp       = *(const us8*)&ob[row][c0];
      *(us8*)(dp + 8) = *(const us8*)&ob[row][c0 + 8];
#endif
    }
  }

  DO_PASS(WTv, V, false)
  #undef DO_PASS
}

// ============ fused edge phase: score + softmax + weighted V aggregation ============
// Depth-2 software pipeline; fp8 K gather (128 B/edge); bf16 V gather (256 B/edge).
__global__ __launch_bounds__(256) void k_sagg(const int* __restrict__ rowptr, const int* __restrict__ csr_src,
                                              const u16* __restrict__ Q, const u16* __restrict__ K,
                                              const u16* __restrict__ V, u16* __restrict__ wV, int N){
  __shared__ float wx[4][64];
  int w = threadIdx.x >> 6, l = threadIdx.x & 63;
  int n = blockIdx.x*4 + w;
  if (n >= N) return;
  int j8 = l >> 3, hh = l & 7, d0 = l * 2;

  f32x2 qf[8];
  {
    const unsigned* qp = (const unsigned*)(Q + (size_t)n*NDIM + hh*16);
    #pragma unroll
    for (int t = 0; t < 8; t++){
      unsigned u = qp[t];
      qf[t].x = blo(u) * 0.25f;
      qf[t].y = bhi(u) * 0.25f;
    }
  }

  int e0 = rowptr[n], e1 = rowptr[n+1];
  int i0 = __builtin_amdgcn_readfirstlane(e0);
  int deg = e1 - e0;
  int nw  = deg >> 3;
  int rem = deg & 7;

  float ssum_l = 0.f;
  f32x2 a01 = {0.f, 0.f};

#if HAVE_FP8
  const u8* Kb = (const u8*)K;
  uint4 kA, kB;
  #define KLOAD(dst_, sidx) dst_ = *(const uint4*)(Kb + (size_t)(sidx)*NDIM + (hh << 4));
  #define KDOTP(p, kk) { \
    f32x2 p2 = {0.f, 0.f}; \
    p2 += qf[0] * __builtin_amdgcn_cvt_pk_f32_fp8((int)kk.x, false); \
    p2 += qf[1] * __builtin_amdgcn_cvt_pk_f32_fp8((int)kk.x, true); \
    p2 += qf[2] * __builtin_amdgcn_cvt_pk_f32_fp8((int)kk.y, false); \
    p2 += qf[3] * __builtin_amdgcn_cvt_pk_f32_fp8((int)kk.y, true); \
    p2 += qf[4] * __builtin_amdgcn_cvt_pk_f32_fp8((int)kk.z, false); \
    p2 += qf[5] * __builtin_amdgcn_cvt_pk_f32_fp8((int)kk.z, true); \
    p2 += qf[6] * __builtin_amdgcn_cvt_pk_f32_fp8((int)kk.w, false); \
    p2 += qf[7] * __builtin_amdgcn_cvt_pk_f32_fp8((int)kk.w, true); \
    p = p2.x + p2.y; }
#else
  struct krow { uint4 lo, hi; };
  krow kA, kB;
  #define KLOAD(dst_, sidx) { \
    const uint4* kp_ = (const uint4*)(K + (size_t)(sidx)*NDIM + hh*16); \
    dst_.lo = kp_[0]; dst_.hi = kp_[1]; }
  #define KDOTP(p, kk) { \
    f32x2 p2 = {0.f, 0.f}; \
    p2 += qf[0] * b2f2(kk.lo.x); p2 += qf[1] * b2f2(kk.lo.y); \
    p2 += qf[2] * b2f2(kk.lo.z); p2 += qf[3] * b2f2(kk.lo.w); \
    p2 += qf[4] * b2f2(kk.hi.x); p2 += qf[5] * b2f2(kk.hi.y); \
    p2 += qf[6] * b2f2(kk.hi.z); p2 += qf[7] * b2f2(kk.hi.w); \
    p = p2.x + p2.y; }
#endif

  unsigned vvA[8], vvB[8];

  if (nw >= 1){
    int s0=csr_src[i0+0], s1=csr_src[i0+1], s2=csr_src[i0+2], s3=csr_src[i0+3];
    int s4=csr_src[i0+4], s5=csr_src[i0+5], s6=csr_src[i0+6], s7=csr_src[i0+7];
    vvA[0] = *(const unsigned*)(V + (size_t)s0*NDIM + d0);
    vvA[1] = *(const unsigned*)(V + (size_t)s1*NDIM + d0);
    vvA[2] = *(const unsigned*)(V + (size_t)s2*NDIM + d0);
    vvA[3] = *(const unsigned*)(V + (size_t)s3*NDIM + d0);
    vvA[4] = *(const unsigned*)(V + (size_t)s4*NDIM + d0);
    vvA[5] = *(const unsigned*)(V + (size_t)s5*NDIM + d0);
    vvA[6] = *(const unsigned*)(V + (size_t)s6*NDIM + d0);
    vvA[7] = *(const unsigned*)(V + (size_t)s7*NDIM + d0);
    int sidx = csr_src[e0 + j8];
    KLOAD(kA, sidx)
  }

  for (int wi = 0; wi < nw; wi++){
    if (wi + 1 < nw){
      int ib = i0 + wi*8 + 8;
      int s0=csr_src[ib+0], s1=csr_src[ib+1], s2=csr_src[ib+2], s3=csr_src[ib+3];
      int s4=csr_src[ib+4], s5=csr_src[ib+5], s6=csr_src[ib+6], s7=csr_src[ib+7];
      vvB[0] = *(const unsigned*)(V + (size_t)s0*NDIM + d0);
      vvB[1] = *(const unsigned*)(V + (size_t)s1*NDIM + d0);
      vvB[2] = *(const unsigned*)(V + (size_t)s2*NDIM + d0);
      vvB[3] = *(const unsigned*)(V + (size_t)s3*NDIM + d0);
      vvB[4] = *(const unsigned*)(V + (size_t)s4*NDIM + d0);
      vvB[5] = *(const unsigned*)(V + (size_t)s5*NDIM + d0);
      vvB[6] = *(const unsigned*)(V + (size_t)s6*NDIM + d0);
      vvB[7] = *(const unsigned*)(V + (size_t)s7*NDIM + d0);
      int sidx = csr_src[e0 + wi*8 + 8 + j8];
      KLOAD(kB, sidx)
    }
    float p;
    KDOTP(p, kA)
    p = fminf(5.f, fmaxf(-5.f, p));
    float wgt = __expf(p);
    ssum_l += wgt;
    wx[w][hh*8 + j8] = wgt;
    float4 wa = *(const float4*)&wx[w][j8*8];
    float4 wb = *(const float4*)&wx[w][j8*8 + 4];
    a01 += b2f2(vvA[0]) * wa.x;
    a01 += b2f2(vvA[1]) * wa.y;
    a01 += b2f2(vvA[2]) * wa.z;
    a01 += b2f2(vvA[3]) * wa.w;
    a01 += b2f2(vvA[4]) * wb.x;
    a01 += b2f2(vvA[5]) * wb.y;
    a01 += b2f2(vvA[6]) * wb.z;
    a01 += b2f2(vvA[7]) * wb.w;
    if (wi + 1 < nw){
      #pragma unroll
      for (int j = 0; j < 8; j++) vvA[j] = vvB[j];
      kA = kB;
    }
  }

  if (rem > 0){
    int i0t = i0 + nw*8;
    int s[8];
    #pragma unroll
    for (int j = 0; j < 8; j++) s[j] = csr_src[i0t + (j < rem ? j : 0)];
    unsigned vv[8];
    #pragma unroll
    for (int j = 0; j < 8; j++) vv[j] = *(const unsigned*)(V + (size_t)s[j]*NDIM + d0);
    int sidx = csr_src[i0t + (j8 < rem ? j8 : 0)];
#if HAVE_FP8
    uint4 kT;
#else
    krow kT;
#endif
    KLOAD(kT, sidx)
    float p;
    KDOTP(p, kT)
    p = fminf(5.f, fmaxf(-5.f, p));
    float wgt = (j8 < rem) ? __expf(p) : 0.f;
    ssum_l += wgt;
    wx[w][hh*8 + j8] = wgt;
    float4 wa = *(const float4*)&wx[w][j8*8];
    float4 wb = *(const float4*)&wx[w][j8*8 + 4];
    a01 += b2f2(vv[0]) * wa.x;
    a01 += b2f2(vv[1]) * wa.y;
    a01 += b2f2(vv[2]) * wa.z;
    a01 += b2f2(vv[3]) * wa.w;
    a01 += b2f2(vv[4]) * wb.x;
    a01 += b2f2(vv[5]) * wb.y;
    a01 += b2f2(vv[6]) * wb.z;
    a01 += b2f2(vv[7]) * wb.w;
  }
  #undef KLOAD
  #undef KDOTP

  ssum_l += __shfl_xor(ssum_l, 8);
  ssum_l += __shfl_xor(ssum_l, 16);
  ssum_l += __shfl_xor(ssum_l, 32);
  float ssum = __shfl(ssum_l, j8);
  float inv = (e1 > e0) ? 1.f/ssum : 0.f;
  unsigned pk = (unsigned)f2b(a01.x*inv) | (((unsigned)f2b(a01.y*inv)) << 16);
  *(unsigned*)(wV + (size_t)n*NDIM + d0) = pk;
}

// ============ O-projection + residual (MFMA, 32-row tiles, coalesced epilogue) ============
__global__ __launch_bounds__(256) void k_h2(const u16* __restrict__ wV, const u16* __restrict__ WTo,
                                            const float* __restrict__ bo, const float* __restrict__ h,
                                            float* __restrict__ h2, int N){
  __shared__ u16 tw[32][136];
  __shared__ float ob[32][132];
  int t = threadIdx.x; int r0 = blockIdx.x * 32;
  int row = t >> 3, c0 = (t & 7) * 16;
  {
    int rr = r0 + row;
    us8 z = {0,0,0,0,0,0,0,0};
    const u16* sp = wV + (size_t)rr*NDIM + c0;
    *(us8*)&tw[row][c0]     = (rr < N) ? *(const us8*)sp       : z;
    *(us8*)&tw[row][c0 + 8] = (rr < N) ? *(const us8*)(sp + 8) : z;
  }
  __syncthreads();
  int lane = t & 63, w = t >> 6;
  int lr = lane & 15, kg = lane >> 4;
  f32x4 zero = {0.f,0.f,0.f,0.f};
  f32x4 acc[2][2];
  #pragma unroll
  for (int n = 0; n < 2; n++)
    #pragma unroll
    for (int m = 0; m < 2; m++) acc[n][m] = zero;
  gemm_tiles<2,2,4,128,136>(&tw[0][0], WTo, lr, kg, w*32, acc);
  #pragma unroll
  for (int n = 0; n < 2; n++){
    int col = w*32 + n*16 + lr;
    float bb = bo[col];
    #pragma unroll
    for (int m = 0; m < 2; m++)
      #pragma unroll
      for (int r = 0; r < 4; r++)
        ob[m*16 + kg*4 + r][col] = acc[n][m][r] + bb;
  }
  __syncthreads();
  if (r0 + row < N){
    const float* hp = h  + (size_t)(r0 + row)*NDIM + c0;
    float*       op = h2 + (size_t)(r0 + row)*NDIM + c0;
    #pragma unroll
    for (int j = 0; j < 4; j++){
      float4 hv = *(const float4*)(hp + 4*j);
      float4 o;
      o.x = ob[row][c0 + 4*j]     + hv.x;
      o.y = ob[row][c0 + 4*j + 1] + hv.y;
      o.z = ob[row][c0 + 4*j + 2] + hv.z;
      o.w = ob[row][c0 + 4*j + 3] + hv.w;
      *(float4*)(op + 4*j) = o;
    }
  }
}

// ============ BN2-apply + FFN + residual (MFMA, 32-row tiles, coalesced epilogue) ============
__global__ __launch_bounds__(256) void k_ffn(const float* __restrict__ h2, const float* __restrict__ scsh,
                                             const u16* __restrict__ WT1, const float* __restrict__ b1,
                                             const u16* __restrict__ WT2, const float* __restrict__ b2,
                                             float* __restrict__ out, int N){
  __shared__ u16 x[32][136];
  __shared__ u16 tt[32][264];          // reused as float [32][132] after GEMM2
  int t = threadIdx.x; int r0 = blockIdx.x * 32;
  int row = t >> 3, c0 = (t & 7) * 16;
  {
    int rr = r0 + row;
    #pragma unroll
    for (int j = 0; j < 4; j++){
      int c = c0 + 4*j;
      float4 v = make_float4(0.f,0.f,0.f,0.f);
      if (rr < N) v = *(const float4*)(h2 + (size_t)rr*NDIM + c);
      us4 o;
      o.x = f2b(v.x * scsh[c]   + scsh[128+c]);
      o.y = f2b(v.y * scsh[c+1] + scsh[129+c]);
      o.z = f2b(v.z * scsh[c+2] + scsh[130+c]);
      o.w = f2b(v.w * scsh[c+3] + scsh[131+c]);
      *(us4*)&x[row][c] = o;
    }
  }
  __syncthreads();
  int lane = t & 63, w = t >> 6;
  int lr = lane & 15, kg = lane >> 4;
  f32x4 zero = {0.f,0.f,0.f,0.f};
  {
    f32x4 a1[4][2];
    #pragma unroll
    for (int n = 0; n < 4; n++)
      #pragma unroll
      for (int m = 0; m < 2; m++) a1[n][m] = zero;
    gemm_tiles<4,2,4,128,136>(&x[0][0], WT1, lr, kg, w*64, a1);
    #pragma unroll
    for (int n = 0; n < 4; n++){
      int col = w*64 + n*16 + lr;
      float bb = b1[col];
      #pragma unroll
      for (int m = 0; m < 2; m++)
        #pragma unroll
        for (int r = 0; r < 4; r++)
          tt[m*16 + kg*4 + r][col] = f2b(fmaxf(a1[n][m][r] + bb, 0.f));
    }
  }
  __syncthreads();
  f32x4 a2[2][2];
  #pragma unroll
  for (int n = 0; n < 2; n++)
    #pragma unroll
    for (int m = 0; m < 2; m++) a2[n][m] = zero;
  gemm_tiles<2,2,8,256,264>(&tt[0][0], WT2, lr, kg, w*32, a2);
  __syncthreads();
  float* ob2 = (float*)&tt[0][0];       // [32][132] overlay
  #pragma unroll
  for (int n = 0; n < 2; n++){
    int col = w*32 + n*16 + lr;
    float bb = b2[col];
    #pragma unroll
    for (int m = 0; m < 2; m++)
      #pragma unroll
      for (int r = 0; r < 4; r++)
        ob2[(m*16 + kg*4 + r)*132 + col] = a2[n][m][r] + bb;
  }
  __syncthreads();
  if (r0 + row < N){
    const float* hp = h2  + (size_t)(r0 + row)*NDIM + c0;
    float*       op = out + (size_t)(r0 + row)*NDIM + c0;
    #pragma unroll
    for (int j = 0; j < 4; j++){
      float4 hv = *(const float4*)(hp + 4*j);
      float4 o;
      o.x = ob2[row*132 + c0 + 4*j]     + hv.x;
      o.y = ob2[row*132 + c0 + 4*j + 1] + hv.y;
      o.z = ob2[row*132 + c0 + 4*j + 2] + hv.z;
      o.w = ob2[row*132 + c0 + 4*j + 3] + hv.w;
      *(float4*)(op + 4*j) = o;
    }
  }
}

extern "C" void kernel_launch(void* const* d_in, const int* in_sizes, int n_in,
                              void* d_out, int out_size, void* d_ws, size_t ws_size,
                              hipStream_t stream) {
  const float* h    = (const float*)d_in[0];
  const int*   src  = (const int*)d_in[1];
  const int*   dst  = (const int*)d_in[2];
  const float* Wq   = (const float*)d_in[3];
  const float* Wk   = (const float*)d_in[4];
  const float* Wv   = (const float*)d_in[5];
  const float* Wo   = (const float*)d_in[6];
  const float* bo   = (const float*)d_in[7];
  const float* bn1g = (const float*)d_in[8];
  const float* bn1b = (const float*)d_in[9];
  const float* bn2g = (const float*)d_in[10];
  const float* bn2b = (const float*)d_in[11];
  const float* W1   = (const float*)d_in[12];
  const float* b1   = (const float*)d_in[13];
  const float* W2   = (const float*)d_in[14];
  const float* b2   = (const float*)d_in[15];
  float* out = (float*)d_out;

  int N = in_sizes[0] / NDIM;
  int E = in_sizes[1];
  size_t fN = (size_t)N * NDIM;

  int B   = (N + 255) >> 8;       // coarse buckets (256 nodes each), <= 256
  int C   = (E + 4095) >> 12;     // edge chunks (4096 edges each)
  int NB2 = B * C;
  int nb2 = (NB2 + 255) / 256;    // <= 256
  int nBn = (N + 127) / 128;
  int n32 = (N + 31) / 32;

  u16* Q  = (u16*)d_ws;
  u16* K  = Q + fN;               // fp8 path uses first fN BYTES of this 2*fN-byte slot
  u16* V  = K + fN;
  u16* wV = Q;                    // reuse: each wave reads Q[n] before writing wV[n]
  float* h2   = (float*)(V + fN);
  int2* ebuf  = (int2*)(h2 + fN);
  int* rowptr = (int*)(ebuf + E);
  int* bsum   = rowptr + (N + 1);
  int* cntT   = bsum + 256;
  int* scn    = cntT + NB2;
  int* csr_src= scn + NB2;
  float* part1 = (float*)(csr_src + E);       // nBn*256
  float* part2 = part1 + (size_t)nBn*256;     // nBn*256
  float* scsh1 = part2 + (size_t)nBn*256;     // 256
  float* scsh2 = scsh1 + 256;                 // 256
  u16* wtq = (u16*)(scsh2 + 256);
  u16* wtk = wtq + NDIM*NDIM;
  u16* wtv = wtk + NDIM*NDIM;
  u16* wto = wtv + NDIM*NDIM;
  u16* wt1 = wto + NDIM*NDIM;
  u16* wt2 = wt1 + NDIM*2*NDIM;

  k_pro<<<nBn + 32 + C, 256, 0, stream>>>(Wq, Wk, Wv, Wo, W1, W2,
                                          wtq, wtk, wtv, wto, wt1, wt2,
                                          h, part1, dst, cntT, nBn, N, E, B, C);
  k_bnf_scan<<<1 + nb2, 256, 0, stream>>>(part1, nBn, bn1g, bn1b, scsh1, N, cntT, bsum, NB2);
  k_scan_top<<<1, 256, 0, stream>>>(bsum, nb2, rowptr, N, E);
  k_scan_down<<<nb2, 256, 0, stream>>>(cntT, bsum, scn, NB2);

  k_qkv_bucket<<<C + n32, 256, 0, stream>>>(h, scsh1, wtq, wtk, wtv, Q, K, V, N,
                                            src, dst, scn, ebuf, B, C, E);
  k_finesort<<<B, 256, 0, stream>>>(ebuf, scn, rowptr, csr_src, B, C, N, E);

  k_sagg<<<(N + 3)/4, 256, 0, stream>>>(rowptr, csr_src, Q, K, V, wV, N);

  k_h2<<<n32, 256, 0, stream>>>(wV, wto, bo, h, h2, N);
  k_bnstats<<<nBn, 256, 0, stream>>>(h2, part2, N);
  k_bn_final<<<1, 256, 0, stream>>>(part2, nBn, bn2g, bn2b, scsh2, N);
  k_ffn<<<n32, 256, 0, stream>>>(h2, scsh2, wt1, b1, wt2, b2, out, N);
}

// Round 16
// 207.063 us; speedup vs baseline: 1.1927x; 1.1659x over previous
//
#include <hip/hip_runtime.h>
#include <hip/hip_bf16.h>

#define NDIM 128
#define NHEAD 8
#define EPSV 1e-5f

#if defined(__has_builtin)
#  if __has_builtin(__builtin_amdgcn_cvt_pk_fp8_f32) && __has_builtin(__builtin_amdgcn_cvt_pk_f32_fp8)
#    define HAVE_FP8 1
#  else
#    define HAVE_FP8 0
#  endif
#else
#  define HAVE_FP8 0
#endif

typedef unsigned short u16;
typedef unsigned char u8;
using bf16x8 = __attribute__((ext_vector_type(8))) short;
using f32x4  = __attribute__((ext_vector_type(4))) float;
using f32x2  = __attribute__((ext_vector_type(2))) float;
using us8    = __attribute__((ext_vector_type(8))) unsigned short;
using us4    = __attribute__((ext_vector_type(4))) unsigned short;

__device__ __forceinline__ u16 f2b(float x){
  union { float f; unsigned u; } v; v.f = x;
  unsigned r = v.u + 0x7FFFu + ((v.u >> 16) & 1u);
  return (u16)(r >> 16);
}
__device__ __forceinline__ float b2f(u16 u){
  union { unsigned u; float f; } v; v.u = ((unsigned)u) << 16; return v.f;
}
__device__ __forceinline__ float blo(unsigned u){
  union { unsigned u; float f; } v; v.u = u << 16; return v.f;
}
__device__ __forceinline__ float bhi(unsigned u){
  union { unsigned u; float f; } v; v.u = u & 0xFFFF0000u; return v.f;
}
__device__ __forceinline__ f32x2 b2f2(unsigned u){
  f32x2 r; r.x = blo(u); r.y = bhi(u); return r;
}

// A-frag: lane provides A[lane%16][(lane/16)*8 + j]; B-frag: B[(lane/16)*8+j][lane%16]
// C/D: col = lane&15, row = (lane>>4)*4 + reg   (measured m89)
template<int NT, int MT, int KS, int WTLD, int XSTR>
__device__ __forceinline__ void gemm_tiles(const u16* X, const u16* __restrict__ WT,
                                           int lr, int kg, int colbase, f32x4 (&acc)[NT][MT]){
  #pragma unroll
  for (int ks = 0; ks < KS; ks++){
    bf16x8 a[MT];
    #pragma unroll
    for (int m = 0; m < MT; m++)
      a[m] = *(const bf16x8*)(X + (size_t)(m*16 + lr)*XSTR + ks*32 + kg*8);
    #pragma unroll
    for (int n = 0; n < NT; n++){
      int col = colbase + n*16 + lr;
      bf16x8 b = *(const bf16x8*)(WT + (size_t)col*WTLD + ks*32 + kg*8);
      #pragma unroll
      for (int m = 0; m < MT; m++)
        acc[n][m] = __builtin_amdgcn_mfma_f32_16x16x32_bf16(a[m], b, acc[n][m], 0, 0, 0);
    }
  }
}

// transpose one 64x64 tile of W (rows x cols, f32) into WT (cols x rows, bf16)
__device__ __forceinline__ void wconv_tile(const float* __restrict__ W, u16* __restrict__ WT,
                                           int rows, int cols, int tr, int tc, int t){
  __shared__ u16 T[64][66];
  int r0 = tr*64, c0 = tc*64;
  int r = t >> 2, cq = (t & 3) * 16;
  const float* src = W + (size_t)(r0 + r)*cols + c0 + cq;
  #pragma unroll
  for (int j = 0; j < 4; j++){
    float4 v = *(const float4*)(src + 4*j);
    us4 o; o.x = f2b(v.x); o.y = f2b(v.y); o.z = f2b(v.z); o.w = f2b(v.w);
    *(us4*)&T[r][cq + 4*j] = o;
  }
  __syncthreads();
  int c = t >> 2, rq = (t & 3) * 16;
  us8 o0, o1;
  #pragma unroll
  for (int j = 0; j < 8; j++){ o0[j] = T[rq + j][c]; o1[j] = T[rq + 8 + j][c]; }
  u16* dstp = WT + (size_t)(c0 + c)*rows + r0 + rq;
  *(us8*)dstp = o0;
  *(us8*)(dstp + 8) = o1;
}

// ============ pro: BN1 partials (nBn, f32x4) + weight transpose (32) + coarse histogram (C) ============
__global__ __launch_bounds__(256) void k_pro(
    const float* __restrict__ Wq, const float* __restrict__ Wk, const float* __restrict__ Wv,
    const float* __restrict__ Wo, const float* __restrict__ W1, const float* __restrict__ W2,
    u16* __restrict__ wtq, u16* __restrict__ wtk, u16* __restrict__ wtv,
    u16* __restrict__ wto, u16* __restrict__ wt1, u16* __restrict__ wt2,
    const float* __restrict__ h, float* __restrict__ part1,
    const int* __restrict__ dst, int* __restrict__ cntT,
    int nBn, int N, int E, int B, int C){
  __shared__ f32x4 lsS[256], lsQ[256];
  __shared__ int hist[256];
  int b = blockIdx.x, t = threadIdx.x;
  if (b < nBn){
    int qd = t & 31, rl = t >> 5;
    int r0 = b * 128;
    f32x4 s = {0.f,0.f,0.f,0.f}, sq = {0.f,0.f,0.f,0.f};
    for (int r = rl; r < 128; r += 8){
      int row = r0 + r;
      if (row < N){
        f32x4 v = *(const f32x4*)(h + (size_t)row*NDIM + qd*4);
        s += v; sq += v*v;
      }
    }
    lsS[t] = s; lsQ[t] = sq; __syncthreads();
    if (rl < 4){ lsS[t] += lsS[t+128]; lsQ[t] += lsQ[t+128]; } __syncthreads();
    if (rl < 2){ lsS[t] += lsS[t+64];  lsQ[t] += lsQ[t+64];  } __syncthreads();
    if (rl == 0){
      f32x4 S  = lsS[t] + lsS[t+32];
      f32x4 Qv = lsQ[t] + lsQ[t+32];
      *(f32x4*)&part1[(size_t)b*256 + qd*4]       = S;
      *(f32x4*)&part1[(size_t)b*256 + 128 + qd*4] = Qv;
    }
    return;
  }
  b -= nBn;
  if (b < 16){
    const float* Ws[4] = {Wq, Wk, Wv, Wo};
    u16* Ts[4] = {wtq, wtk, wtv, wto};
    int wi = b >> 2, ti = b & 3;
    wconv_tile(Ws[wi], Ts[wi], 128, 128, ti >> 1, ti & 1, t);
    return;
  }
  if (b < 24){
    int ti = b - 16;
    wconv_tile(W1, wt1, 128, 256, ti >> 2, ti & 3, t);
    return;
  }
  if (b < 32){
    int ti = b - 24;
    wconv_tile(W2, wt2, 256, 128, ti & 3, ti >> 2, t);
    return;
  }
  int ci = b - 32;
  if (ci >= C) return;
  hist[t] = 0; __syncthreads();
  int e0 = ci * 4096;
  #pragma unroll
  for (int j = 0; j < 16; j++){
    int e = e0 + t + j*256;
    if (e < E) atomicAdd(&hist[dst[e] >> 8], 1);
  }
  __syncthreads();
  if (t < B) cntT[t*C + ci] = hist[t];
}

// deterministic partials reduce: acc[t] = sum_i part[i*256 + t]
__device__ __forceinline__ float reduce_part(const float* __restrict__ part, int nP, int t){
  float a0 = 0.f, a1 = 0.f, a2 = 0.f, a3 = 0.f;
  int i = 0;
  for (; i + 4 <= nP; i += 4){
    a0 += part[(size_t)(i+0)*256 + t];
    a1 += part[(size_t)(i+1)*256 + t];
    a2 += part[(size_t)(i+2)*256 + t];
    a3 += part[(size_t)(i+3)*256 + t];
  }
  for (; i < nP; i++) a0 += part[(size_t)i*256 + t];
  return (a0 + a1) + (a2 + a3);
}

// ============ block 0: BN1 reduce+finalize; blocks 1..: scan partials over cntT ============
__global__ __launch_bounds__(256) void k_bnf_scan(
    const float* __restrict__ part1, int nBn,
    const float* __restrict__ g, const float* __restrict__ b_,
    float* __restrict__ scsh, int N,
    const int* __restrict__ in, int* __restrict__ bsum, int len){
  __shared__ int ls[256];
  __shared__ float sm[256];
  int t = threadIdx.x, b = blockIdx.x;
  if (b == 0){
    sm[t] = reduce_part(part1, nBn, t);
    __syncthreads();
    if (t < 128){
      float mean = sm[t] / (float)N;
      float var  = sm[128+t] / (float)N - mean*mean;
      float rstd = rsqrtf(var + EPSV);
      float sc = g[t] * rstd;
      scsh[t] = sc; scsh[128+t] = b_[t] - mean*sc;
    }
    return;
  }
  b -= 1;
  int i = b*256 + t;
  ls[t] = (i < len) ? in[i] : 0; __syncthreads();
  for (int off = 128; off > 0; off >>= 1){
    if (t < off) ls[t] += ls[t + off];
    __syncthreads();
  }
  if (t == 0) bsum[b] = ls[0];
}

// ============ BN2 reduce (64 spread-atomic sets) + finalize ============
__global__ __launch_bounds__(256) void k_bn_final(const float* __restrict__ sets,
                                                  const float* __restrict__ g, const float* __restrict__ b,
                                                  float* __restrict__ scsh, int N){
  __shared__ float sm[256];
  int t = threadIdx.x;
  sm[t] = reduce_part(sets, 64, t);
  __syncthreads();
  if (t < 128){
    float mean = sm[t] / (float)N;
    float var  = sm[128+t] / (float)N - mean*mean;
    float rstd = rsqrtf(var + EPSV);
    float sc = g[t] * rstd;
    scsh[t] = sc; scsh[128+t] = b[t] - mean*sc;
  }
}

__global__ __launch_bounds__(256) void k_scan_top(int* __restrict__ bsum, int nb, int* __restrict__ rowptr, int N, int E){
  __shared__ int ls[256];
  int t = threadIdx.x;
  int v = (t < nb) ? bsum[t] : 0; ls[t] = v; __syncthreads();
  for (int off = 1; off < 256; off <<= 1){
    int add = (t >= off) ? ls[t - off] : 0;
    __syncthreads();
    ls[t] += add;
    __syncthreads();
  }
  if (t < nb) bsum[t] = ls[t] - v;
  if (t == 0) rowptr[N] = E;
}

__global__ __launch_bounds__(256) void k_scan_down(const int* __restrict__ in, const int* __restrict__ bsum,
                                                   int* __restrict__ outp, int len){
  __shared__ int ls[256];
  int t = threadIdx.x; int i = blockIdx.x*256 + t;
  int v = (i < len) ? in[i] : 0; ls[t] = v; __syncthreads();
  for (int off = 1; off < 256; off <<= 1){
    int add = (t >= off) ? ls[t - off] : 0;
    __syncthreads();
    ls[t] += add;
    __syncthreads();
  }
  if (i < len) outp[i] = ls[t] - v + bsum[blockIdx.x];
}

// ============ fine sort within bucket: rowptr + csr_src (LDS atomics only) ============
__global__ __launch_bounds__(256) void k_finesort(const int2* __restrict__ ebuf, const int* __restrict__ scn,
                                                  int* __restrict__ rowptr, int* __restrict__ csr_src,
                                                  int B, int C, int N, int E){
  __shared__ int ls[256], cur[256];
  int b = blockIdx.x, t = threadIdx.x;
  int base = scn[b*C];
  int end  = (b == B-1) ? E : scn[(b+1)*C];
  int lo = b << 8;
  cur[t] = 0; __syncthreads();
  for (int e = base + t; e < end; e += 256) atomicAdd(&cur[ebuf[e].x - lo], 1);
  __syncthreads();
  int v = cur[t]; ls[t] = v; __syncthreads();
  for (int off = 1; off < 256; off <<= 1){
    int add = (t >= off) ? ls[t - off] : 0;
    __syncthreads();
    ls[t] += add;
    __syncthreads();
  }
  int excl = ls[t] - v;
  __syncthreads();
  cur[t] = excl;
  if (lo + t < N) rowptr[lo + t] = base + excl;
  __syncthreads();
  for (int e = base + t; e < end; e += 256){
    int2 p = ebuf[e];
    int slot = base + atomicAdd(&cur[p.x - lo], 1);
    csr_src[slot] = p.y;
  }
}

// ============ merged: bucket pass (first C blocks) + BN1-apply + QKV projection (MFMA, 32-row tiles) ============
__global__ __launch_bounds__(256) void k_qkv_bucket(
    const float* __restrict__ h, const float* __restrict__ scsh,
    const u16* __restrict__ WTq, const u16* __restrict__ WTk, const u16* __restrict__ WTv,
    u16* __restrict__ Q, u16* __restrict__ K, u16* __restrict__ V, int N,
    const int* __restrict__ src, const int* __restrict__ dst,
    const int* __restrict__ scn, int2* __restrict__ ebuf, int B, int C, int E){
  __shared__ u16 hn[32][136];
  __shared__ u16 ob[32][136];
  __shared__ int off[256];
  int b = blockIdx.x, t = threadIdx.x;
  if (b < C){
    off[t] = (t < B) ? scn[t*C + b] : 0;
    __syncthreads();
    int e0 = b * 4096;
    #pragma unroll
    for (int j = 0; j < 16; j++){
      int e = e0 + t + j*256;
      if (e < E){
        int d = dst[e], s = src[e];
        int slot = atomicAdd(&off[d >> 8], 1);
        ebuf[slot] = make_int2(d, s);
      }
    }
    return;
  }
  int r0 = (b - C) * 32;
  int row = t >> 3, c0 = (t & 7) * 16;
  {
    int rr = r0 + row;
    #pragma unroll
    for (int j = 0; j < 4; j++){
      int c = c0 + 4*j;
      float4 v = make_float4(0.f,0.f,0.f,0.f);
      if (rr < N) v = *(const float4*)(h + (size_t)rr*NDIM + c);
      us4 o;
      o.x = f2b(v.x * scsh[c]   + scsh[128+c]);
      o.y = f2b(v.y * scsh[c+1] + scsh[129+c]);
      o.z = f2b(v.z * scsh[c+2] + scsh[130+c]);
      o.w = f2b(v.w * scsh[c+3] + scsh[131+c]);
      *(us4*)&hn[row][c] = o;
    }
  }
  __syncthreads();
  int lane = t & 63, w = t >> 6;
  int lr = lane & 15, kg = lane >> 4;
  f32x4 zero = {0.f,0.f,0.f,0.f};

  #define DO_PASS(WT, OUT, FIRST) { \
    f32x4 acc[2][2]; \
    _Pragma("unroll") for (int n = 0; n < 2; n++) _Pragma("unroll") for (int m = 0; m < 2; m++) acc[n][m] = zero; \
    gemm_tiles<2,2,4,128,136>(&hn[0][0], WT, lr, kg, w*32, acc); \
    if (!FIRST) __syncthreads(); \
    _Pragma("unroll") for (int n = 0; n < 2; n++){ \
      int col = w*32 + n*16 + lr; \
      _Pragma("unroll") for (int m = 0; m < 2; m++) \
        _Pragma("unroll") for (int r = 0; r < 4; r++) \
          ob[m*16 + kg*4 + r][col] = f2b(acc[n][m][r]); \
    } \
    __syncthreads(); \
    if (r0 + row < N){ \
      u16* dp = OUT + (size_t)(r0 + row)*NDIM + c0; \
      *(us8*)dp       = *(const us8*)&ob[row][c0]; \
      *(us8*)(dp + 8) = *(const us8*)&ob[row][c0 + 8]; \
    } }

  DO_PASS(WTq, Q, true)

  // K pass: GEMM -> ob(bf16) -> fp8 (or bf16 fallback) coalesced store
  {
    f32x4 acc[2][2];
    #pragma unroll
    for (int n = 0; n < 2; n++)
      #pragma unroll
      for (int m = 0; m < 2; m++) acc[n][m] = zero;
    gemm_tiles<2,2,4,128,136>(&hn[0][0], WTk, lr, kg, w*32, acc);
    __syncthreads();
    #pragma unroll
    for (int n = 0; n < 2; n++){
      int col = w*32 + n*16 + lr;
      #pragma unroll
      for (int m = 0; m < 2; m++)
        #pragma unroll
        for (int r = 0; r < 4; r++)
          ob[m*16 + kg*4 + r][col] = f2b(acc[n][m][r]);
    }
    __syncthreads();
    if (r0 + row < N){
#if HAVE_FP8
      u8* dp = (u8*)K + (size_t)(r0 + row)*NDIM + c0;
      unsigned wd[4];
      #pragma unroll
      for (int j = 0; j < 2; j++){
        us8 v = *(const us8*)&ob[row][c0 + 8*j];
        int w0 = __builtin_amdgcn_cvt_pk_fp8_f32(b2f(v[0]), b2f(v[1]), 0, false);
        w0     = __builtin_amdgcn_cvt_pk_fp8_f32(b2f(v[2]), b2f(v[3]), w0, true);
        int w1 = __builtin_amdgcn_cvt_pk_fp8_f32(b2f(v[4]), b2f(v[5]), 0, false);
        w1     = __builtin_amdgcn_cvt_pk_fp8_f32(b2f(v[6]), b2f(v[7]), w1, true);
        wd[2*j] = (unsigned)w0; wd[2*j+1] = (unsigned)w1;
      }
      *(uint4*)dp = make_uint4(wd[0], wd[1], wd[2], wd[3]);
#else
      u16* dp = K + (size_t)(r0 + row)*NDIM + c0;
      *(us8*)dp       = *(const us8*)&ob[row][c0];
      *(us8*)(dp + 8) = *(const us8*)&ob[row][c0 + 8];
#endif
    }
  }

  DO_PASS(WTv, V, false)
  #undef DO_PASS
}

// ============ fused edge phase: score + softmax + weighted V aggregation ============
// Depth-2 software pipeline; fp8 K gather (128 B/edge); bf16 V gather (256 B/edge).
__global__ __launch_bounds__(256) void k_sagg(const int* __restrict__ rowptr, const int* __restrict__ csr_src,
                                              const u16* __restrict__ Q, const u16* __restrict__ K,
                                              const u16* __restrict__ V, u16* __restrict__ wV, int N){
  __shared__ float wx[4][64];
  int w = threadIdx.x >> 6, l = threadIdx.x & 63;
  int n = blockIdx.x*4 + w;
  if (n >= N) return;
  int j8 = l >> 3, hh = l & 7, d0 = l * 2;

  f32x2 qf[8];
  {
    const unsigned* qp = (const unsigned*)(Q + (size_t)n*NDIM + hh*16);
    #pragma unroll
    for (int t = 0; t < 8; t++){
      unsigned u = qp[t];
      qf[t].x = blo(u) * 0.25f;
      qf[t].y = bhi(u) * 0.25f;
    }
  }

  int e0 = rowptr[n], e1 = rowptr[n+1];
  int i0 = __builtin_amdgcn_readfirstlane(e0);
  int deg = e1 - e0;
  int nw  = deg >> 3;
  int rem = deg & 7;

  float ssum_l = 0.f;
  f32x2 a01 = {0.f, 0.f};

#if HAVE_FP8
  const u8* Kb = (const u8*)K;
  uint4 kA, kB;
  #define KLOAD(dst_, sidx) dst_ = *(const uint4*)(Kb + (size_t)(sidx)*NDIM + (hh << 4));
  #define KDOTP(p, kk) { \
    f32x2 p2 = {0.f, 0.f}; \
    p2 += qf[0] * __builtin_amdgcn_cvt_pk_f32_fp8((int)kk.x, false); \
    p2 += qf[1] * __builtin_amdgcn_cvt_pk_f32_fp8((int)kk.x, true); \
    p2 += qf[2] * __builtin_amdgcn_cvt_pk_f32_fp8((int)kk.y, false); \
    p2 += qf[3] * __builtin_amdgcn_cvt_pk_f32_fp8((int)kk.y, true); \
    p2 += qf[4] * __builtin_amdgcn_cvt_pk_f32_fp8((int)kk.z, false); \
    p2 += qf[5] * __builtin_amdgcn_cvt_pk_f32_fp8((int)kk.z, true); \
    p2 += qf[6] * __builtin_amdgcn_cvt_pk_f32_fp8((int)kk.w, false); \
    p2 += qf[7] * __builtin_amdgcn_cvt_pk_f32_fp8((int)kk.w, true); \
    p = p2.x + p2.y; }
#else
  struct krow { uint4 lo, hi; };
  krow kA, kB;
  #define KLOAD(dst_, sidx) { \
    const uint4* kp_ = (const uint4*)(K + (size_t)(sidx)*NDIM + hh*16); \
    dst_.lo = kp_[0]; dst_.hi = kp_[1]; }
  #define KDOTP(p, kk) { \
    f32x2 p2 = {0.f, 0.f}; \
    p2 += qf[0] * b2f2(kk.lo.x); p2 += qf[1] * b2f2(kk.lo.y); \
    p2 += qf[2] * b2f2(kk.lo.z); p2 += qf[3] * b2f2(kk.lo.w); \
    p2 += qf[4] * b2f2(kk.hi.x); p2 += qf[5] * b2f2(kk.hi.y); \
    p2 += qf[6] * b2f2(kk.hi.z); p2 += qf[7] * b2f2(kk.hi.w); \
    p = p2.x + p2.y; }
#endif

  unsigned vvA[8], vvB[8];

  if (nw >= 1){
    int s0=csr_src[i0+0], s1=csr_src[i0+1], s2=csr_src[i0+2], s3=csr_src[i0+3];
    int s4=csr_src[i0+4], s5=csr_src[i0+5], s6=csr_src[i0+6], s7=csr_src[i0+7];
    vvA[0] = *(const unsigned*)(V + (size_t)s0*NDIM + d0);
    vvA[1] = *(const unsigned*)(V + (size_t)s1*NDIM + d0);
    vvA[2] = *(const unsigned*)(V + (size_t)s2*NDIM + d0);
    vvA[3] = *(const unsigned*)(V + (size_t)s3*NDIM + d0);
    vvA[4] = *(const unsigned*)(V + (size_t)s4*NDIM + d0);
    vvA[5] = *(const unsigned*)(V + (size_t)s5*NDIM + d0);
    vvA[6] = *(const unsigned*)(V + (size_t)s6*NDIM + d0);
    vvA[7] = *(const unsigned*)(V + (size_t)s7*NDIM + d0);
    int sidx = csr_src[e0 + j8];
    KLOAD(kA, sidx)
  }

  for (int wi = 0; wi < nw; wi++){
    if (wi + 1 < nw){
      int ib = i0 + wi*8 + 8;
      int s0=csr_src[ib+0], s1=csr_src[ib+1], s2=csr_src[ib+2], s3=csr_src[ib+3];
      int s4=csr_src[ib+4], s5=csr_src[ib+5], s6=csr_src[ib+6], s7=csr_src[ib+7];
      vvB[0] = *(const unsigned*)(V + (size_t)s0*NDIM + d0);
      vvB[1] = *(const unsigned*)(V + (size_t)s1*NDIM + d0);
      vvB[2] = *(const unsigned*)(V + (size_t)s2*NDIM + d0);
      vvB[3] = *(const unsigned*)(V + (size_t)s3*NDIM + d0);
      vvB[4] = *(const unsigned*)(V + (size_t)s4*NDIM + d0);
      vvB[5] = *(const unsigned*)(V + (size_t)s5*NDIM + d0);
      vvB[6] = *(const unsigned*)(V + (size_t)s6*NDIM + d0);
      vvB[7] = *(const unsigned*)(V + (size_t)s7*NDIM + d0);
      int sidx = csr_src[e0 + wi*8 + 8 + j8];
      KLOAD(kB, sidx)
    }
    float p;
    KDOTP(p, kA)
    p = fminf(5.f, fmaxf(-5.f, p));
    float wgt = __expf(p);
    ssum_l += wgt;
    wx[w][hh*8 + j8] = wgt;
    float4 wa = *(const float4*)&wx[w][j8*8];
    float4 wb = *(const float4*)&wx[w][j8*8 + 4];
    a01 += b2f2(vvA[0]) * wa.x;
    a01 += b2f2(vvA[1]) * wa.y;
    a01 += b2f2(vvA[2]) * wa.z;
    a01 += b2f2(vvA[3]) * wa.w;
    a01 += b2f2(vvA[4]) * wb.x;
    a01 += b2f2(vvA[5]) * wb.y;
    a01 += b2f2(vvA[6]) * wb.z;
    a01 += b2f2(vvA[7]) * wb.w;
    if (wi + 1 < nw){
      #pragma unroll
      for (int j = 0; j < 8; j++) vvA[j] = vvB[j];
      kA = kB;
    }
  }

  if (rem > 0){
    int i0t = i0 + nw*8;
    int s[8];
    #pragma unroll
    for (int j = 0; j < 8; j++) s[j] = csr_src[i0t + (j < rem ? j : 0)];
    unsigned vv[8];
    #pragma unroll
    for (int j = 0; j < 8; j++) vv[j] = *(const unsigned*)(V + (size_t)s[j]*NDIM + d0);
    int sidx = csr_src[i0t + (j8 < rem ? j8 : 0)];
#if HAVE_FP8
    uint4 kT;
#else
    krow kT;
#endif
    KLOAD(kT, sidx)
    float p;
    KDOTP(p, kT)
    p = fminf(5.f, fmaxf(-5.f, p));
    float wgt = (j8 < rem) ? __expf(p) : 0.f;
    ssum_l += wgt;
    wx[w][hh*8 + j8] = wgt;
    float4 wa = *(const float4*)&wx[w][j8*8];
    float4 wb = *(const float4*)&wx[w][j8*8 + 4];
    a01 += b2f2(vv[0]) * wa.x;
    a01 += b2f2(vv[1]) * wa.y;
    a01 += b2f2(vv[2]) * wa.z;
    a01 += b2f2(vv[3]) * wa.w;
    a01 += b2f2(vv[4]) * wb.x;
    a01 += b2f2(vv[5]) * wb.y;
    a01 += b2f2(vv[6]) * wb.z;
    a01 += b2f2(vv[7]) * wb.w;
  }
  #undef KLOAD
  #undef KDOTP

  ssum_l += __shfl_xor(ssum_l, 8);
  ssum_l += __shfl_xor(ssum_l, 16);
  ssum_l += __shfl_xor(ssum_l, 32);
  float ssum = __shfl(ssum_l, j8);
  float inv = (e1 > e0) ? 1.f/ssum : 0.f;
  unsigned pk = (unsigned)f2b(a01.x*inv) | (((unsigned)f2b(a01.y*inv)) << 16);
  *(unsigned*)(wV + (size_t)n*NDIM + d0) = pk;
}

// ============ O-projection + residual + BN2 partials (spread atomics, 64 sets) ============
__global__ __launch_bounds__(256) void k_h2(const u16* __restrict__ wV, const u16* __restrict__ WTo,
                                            const float* __restrict__ bo, const float* __restrict__ h,
                                            float* __restrict__ h2, float* __restrict__ sets, int N){
  __shared__ u16 tw[32][136];
  __shared__ float ob[32][132];
  int t = threadIdx.x; int r0 = blockIdx.x * 32;
  int row = t >> 3, c0 = (t & 7) * 16;
  {
    int rr = r0 + row;
    us8 z = {0,0,0,0,0,0,0,0};
    const u16* sp = wV + (size_t)rr*NDIM + c0;
    *(us8*)&tw[row][c0]     = (rr < N) ? *(const us8*)sp       : z;
    *(us8*)&tw[row][c0 + 8] = (rr < N) ? *(const us8*)(sp + 8) : z;
  }
  __syncthreads();
  int lane = t & 63, w = t >> 6;
  int lr = lane & 15, kg = lane >> 4;
  f32x4 zero = {0.f,0.f,0.f,0.f};
  f32x4 acc[2][2];
  #pragma unroll
  for (int n = 0; n < 2; n++)
    #pragma unroll
    for (int m = 0; m < 2; m++) acc[n][m] = zero;
  gemm_tiles<2,2,4,128,136>(&tw[0][0], WTo, lr, kg, w*32, acc);
  #pragma unroll
  for (int n = 0; n < 2; n++){
    int col = w*32 + n*16 + lr;
    float bb = bo[col];
    #pragma unroll
    for (int m = 0; m < 2; m++)
      #pragma unroll
      for (int r = 0; r < 4; r++)
        ob[m*16 + kg*4 + r][col] = acc[n][m][r] + bb;
  }
  __syncthreads();
  if (r0 + row < N){
    const float* hp = h  + (size_t)(r0 + row)*NDIM + c0;
    float*       op = h2 + (size_t)(r0 + row)*NDIM + c0;
    #pragma unroll
    for (int j = 0; j < 4; j++){
      float4 hv = *(const float4*)(hp + 4*j);
      float4 o;
      o.x = ob[row][c0 + 4*j]     + hv.x;
      o.y = ob[row][c0 + 4*j + 1] + hv.y;
      o.z = ob[row][c0 + 4*j + 2] + hv.z;
      o.w = ob[row][c0 + 4*j + 3] + hv.w;
      *(float4*)(op + 4*j) = o;
      ob[row][c0 + 4*j]     = o.x;
      ob[row][c0 + 4*j + 1] = o.y;
      ob[row][c0 + 4*j + 2] = o.z;
      ob[row][c0 + 4*j + 3] = o.w;
    }
  } else {
    #pragma unroll
    for (int j = 0; j < 16; j++) ob[row][c0 + j] = 0.f;
  }
  __syncthreads();
  // column partials over 32 rows -> one fire-and-forget atomic per column into set (blockIdx&63)
  int colx = t & 127, hf = t >> 7;
  float s = 0.f, q = 0.f;
  #pragma unroll
  for (int r = 0; r < 16; r++){ float v = ob[hf*16 + r][colx]; s += v; q += v*v; }
  float* cs = (float*)&tw[0][0];
  cs[hf*256 + colx]       = s;
  cs[hf*256 + 128 + colx] = q;
  __syncthreads();
  if (t < 128){
    float* sp = sets + ((size_t)(blockIdx.x & 63) << 8);
    atomicAdd(&sp[t],       cs[t]       + cs[256 + t]);
    atomicAdd(&sp[128 + t], cs[128 + t] + cs[384 + t]);
  }
}

// ============ BN2-apply + FFN + residual (MFMA, 32-row tiles, coalesced epilogue) ============
__global__ __launch_bounds__(256) void k_ffn(const float* __restrict__ h2, const float* __restrict__ scsh,
                                             const u16* __restrict__ WT1, const float* __restrict__ b1,
                                             const u16* __restrict__ WT2, const float* __restrict__ b2,
                                             float* __restrict__ out, int N){
  __shared__ u16 x[32][136];
  __shared__ u16 tt[32][264];          // reused as float [32][132] after GEMM2
  int t = threadIdx.x; int r0 = blockIdx.x * 32;
  int row = t >> 3, c0 = (t & 7) * 16;
  {
    int rr = r0 + row;
    #pragma unroll
    for (int j = 0; j < 4; j++){
      int c = c0 + 4*j;
      float4 v = make_float4(0.f,0.f,0.f,0.f);
      if (rr < N) v = *(const float4*)(h2 + (size_t)rr*NDIM + c);
      us4 o;
      o.x = f2b(v.x * scsh[c]   + scsh[128+c]);
      o.y = f2b(v.y * scsh[c+1] + scsh[129+c]);
      o.z = f2b(v.z * scsh[c+2] + scsh[130+c]);
      o.w = f2b(v.w * scsh[c+3] + scsh[131+c]);
      *(us4*)&x[row][c] = o;
    }
  }
  __syncthreads();
  int lane = t & 63, w = t >> 6;
  int lr = lane & 15, kg = lane >> 4;
  f32x4 zero = {0.f,0.f,0.f,0.f};
  {
    f32x4 a1[4][2];
    #pragma unroll
    for (int n = 0; n < 4; n++)
      #pragma unroll
      for (int m = 0; m < 2; m++) a1[n][m] = zero;
    gemm_tiles<4,2,4,128,136>(&x[0][0], WT1, lr, kg, w*64, a1);
    #pragma unroll
    for (int n = 0; n < 4; n++){
      int col = w*64 + n*16 + lr;
      float bb = b1[col];
      #pragma unroll
      for (int m = 0; m < 2; m++)
        #pragma unroll
        for (int r = 0; r < 4; r++)
          tt[m*16 + kg*4 + r][col] = f2b(fmaxf(a1[n][m][r] + bb, 0.f));
    }
  }
  __syncthreads();
  f32x4 a2[2][2];
  #pragma unroll
  for (int n = 0; n < 2; n++)
    #pragma unroll
    for (int m = 0; m < 2; m++) a2[n][m] = zero;
  gemm_tiles<2,2,8,256,264>(&tt[0][0], WT2, lr, kg, w*32, a2);
  __syncthreads();
  float* ob2 = (float*)&tt[0][0];       // [32][132] overlay
  #pragma unroll
  for (int n = 0; n < 2; n++){
    int col = w*32 + n*16 + lr;
    float bb = b2[col];
    #pragma unroll
    for (int m = 0; m < 2; m++)
      #pragma unroll
      for (int r = 0; r < 4; r++)
        ob2[(m*16 + kg*4 + r)*132 + col] = a2[n][m][r] + bb;
  }
  __syncthreads();
  if (r0 + row < N){
    const float* hp = h2  + (size_t)(r0 + row)*NDIM + c0;
    float*       op = out + (size_t)(r0 + row)*NDIM + c0;
    #pragma unroll
    for (int j = 0; j < 4; j++){
      float4 hv = *(const float4*)(hp + 4*j);
      float4 o;
      o.x = ob2[row*132 + c0 + 4*j]     + hv.x;
      o.y = ob2[row*132 + c0 + 4*j + 1] + hv.y;
      o.z = ob2[row*132 + c0 + 4*j + 2] + hv.z;
      o.w = ob2[row*132 + c0 + 4*j + 3] + hv.w;
      *(float4*)(op + 4*j) = o;
    }
  }
}

extern "C" void kernel_launch(void* const* d_in, const int* in_sizes, int n_in,
                              void* d_out, int out_size, void* d_ws, size_t ws_size,
                              hipStream_t stream) {
  const float* h    = (const float*)d_in[0];
  const int*   src  = (const int*)d_in[1];
  const int*   dst  = (const int*)d_in[2];
  const float* Wq   = (const float*)d_in[3];
  const float* Wk   = (const float*)d_in[4];
  const float* Wv   = (const float*)d_in[5];
  const float* Wo   = (const float*)d_in[6];
  const float* bo   = (const float*)d_in[7];
  const float* bn1g = (const float*)d_in[8];
  const float* bn1b = (const float*)d_in[9];
  const float* bn2g = (const float*)d_in[10];
  const float* bn2b = (const float*)d_in[11];
  const float* W1   = (const float*)d_in[12];
  const float* b1   = (const float*)d_in[13];
  const float* W2   = (const float*)d_in[14];
  const float* b2   = (const float*)d_in[15];
  float* out = (float*)d_out;

  int N = in_sizes[0] / NDIM;
  int E = in_sizes[1];
  size_t fN = (size_t)N * NDIM;

  int B   = (N + 255) >> 8;       // coarse buckets (256 nodes each), <= 256
  int C   = (E + 4095) >> 12;     // edge chunks (4096 edges each)
  int NB2 = B * C;
  int nb2 = (NB2 + 255) / 256;    // <= 256
  int nBn = (N + 127) / 128;
  int n32 = (N + 31) / 32;

  u16* Q  = (u16*)d_ws;
  u16* K  = Q + fN;               // fp8 path uses first fN BYTES of this 2*fN-byte slot
  u16* V  = K + fN;
  u16* wV = Q;                    // reuse: each wave reads Q[n] before writing wV[n]
  float* h2   = (float*)(V + fN);
  int2* ebuf  = (int2*)(h2 + fN);
  int* rowptr = (int*)(ebuf + E);
  int* bsum   = rowptr + (N + 1);
  int* cntT   = bsum + 256;
  int* scn    = cntT + NB2;
  int* csr_src= scn + NB2;
  float* part1 = (float*)(csr_src + E);       // nBn*256
  float* sets2 = part1 + (size_t)nBn*256;     // 64*256
  float* scsh1 = sets2 + 64*256;              // 256
  float* scsh2 = scsh1 + 256;                 // 256
  u16* wtq = (u16*)(scsh2 + 256);
  u16* wtk = wtq + NDIM*NDIM;
  u16* wtv = wtk + NDIM*NDIM;
  u16* wto = wtv + NDIM*NDIM;
  u16* wt1 = wto + NDIM*NDIM;
  u16* wt2 = wt1 + NDIM*2*NDIM;

  hipMemsetAsync(sets2, 0, 64*256*sizeof(float), stream);

  k_pro<<<nBn + 32 + C, 256, 0, stream>>>(Wq, Wk, Wv, Wo, W1, W2,
                                          wtq, wtk, wtv, wto, wt1, wt2,
                                          h, part1, dst, cntT, nBn, N, E, B, C);
  k_bnf_scan<<<1 + nb2, 256, 0, stream>>>(part1, nBn, bn1g, bn1b, scsh1, N, cntT, bsum, NB2);
  k_scan_top<<<1, 256, 0, stream>>>(bsum, nb2, rowptr, N, E);
  k_scan_down<<<nb2, 256, 0, stream>>>(cntT, bsum, scn, NB2);

  k_qkv_bucket<<<C + n32, 256, 0, stream>>>(h, scsh1, wtq, wtk, wtv, Q, K, V, N,
                                            src, dst, scn, ebuf, B, C, E);
  k_finesort<<<B, 256, 0, stream>>>(ebuf, scn, rowptr, csr_src, B, C, N, E);

  k_sagg<<<(N + 3)/4, 256, 0, stream>>>(rowptr, csr_src, Q, K, V, wV, N);

  k_h2<<<n32, 256, 0, stream>>>(wV, wto, bo, h, h2, sets2, N);
  k_bn_final<<<1, 256, 0, stream>>>(sets2, bn2g, bn2b, scsh2, N);
  k_ffn<<<n32, 256, 0, stream>>>(h2, scsh2, wt1, b1, wt2, b2, out, N);
}

// Round 17
// 176.065 us; speedup vs baseline: 1.4027x; 1.1761x over previous
//
#include <hip/hip_runtime.h>
#include <hip/hip_bf16.h>

#define NDIM 128
#define NHEAD 8
#define EPSV 1e-5f

#if defined(__has_builtin)
#  if __has_builtin(__builtin_amdgcn_cvt_pk_fp8_f32) && __has_builtin(__builtin_amdgcn_cvt_pk_f32_fp8)
#    define HAVE_FP8 1
#  else
#    define HAVE_FP8 0
#  endif
#else
#  define HAVE_FP8 0
#endif

typedef unsigned short u16;
typedef unsigned char u8;
using bf16x8 = __attribute__((ext_vector_type(8))) short;
using f32x4  = __attribute__((ext_vector_type(4))) float;
using f32x2  = __attribute__((ext_vector_type(2))) float;
using us8    = __attribute__((ext_vector_type(8))) unsigned short;
using us4    = __attribute__((ext_vector_type(4))) unsigned short;

__device__ __forceinline__ u16 f2b(float x){
  union { float f; unsigned u; } v; v.f = x;
  unsigned r = v.u + 0x7FFFu + ((v.u >> 16) & 1u);
  return (u16)(r >> 16);
}
__device__ __forceinline__ float b2f(u16 u){
  union { unsigned u; float f; } v; v.u = ((unsigned)u) << 16; return v.f;
}
__device__ __forceinline__ float blo(unsigned u){
  union { unsigned u; float f; } v; v.u = u << 16; return v.f;
}
__device__ __forceinline__ float bhi(unsigned u){
  union { unsigned u; float f; } v; v.u = u & 0xFFFF0000u; return v.f;
}
__device__ __forceinline__ f32x2 b2f2(unsigned u){
  f32x2 r; r.x = blo(u); r.y = bhi(u); return r;
}

// A-frag: lane provides A[lane%16][(lane/16)*8 + j]; B-frag: B[(lane/16)*8+j][lane%16]
// C/D: col = lane&15, row = (lane>>4)*4 + reg   (measured m89)
template<int NT, int MT, int KS, int WTLD, int XSTR>
__device__ __forceinline__ void gemm_tiles(const u16* X, const u16* __restrict__ WT,
                                           int lr, int kg, int colbase, f32x4 (&acc)[NT][MT]){
  #pragma unroll
  for (int ks = 0; ks < KS; ks++){
    bf16x8 a[MT];
    #pragma unroll
    for (int m = 0; m < MT; m++)
      a[m] = *(const bf16x8*)(X + (size_t)(m*16 + lr)*XSTR + ks*32 + kg*8);
    #pragma unroll
    for (int n = 0; n < NT; n++){
      int col = colbase + n*16 + lr;
      bf16x8 b = *(const bf16x8*)(WT + (size_t)col*WTLD + ks*32 + kg*8);
      #pragma unroll
      for (int m = 0; m < MT; m++)
        acc[n][m] = __builtin_amdgcn_mfma_f32_16x16x32_bf16(a[m], b, acc[n][m], 0, 0, 0);
    }
  }
}

// transpose one 64x64 tile of W (rows x cols, f32) into WT (cols x rows, bf16)
__device__ __forceinline__ void wconv_tile(const float* __restrict__ W, u16* __restrict__ WT,
                                           int rows, int cols, int tr, int tc, int t){
  __shared__ u16 T[64][66];
  int r0 = tr*64, c0 = tc*64;
  int r = t >> 2, cq = (t & 3) * 16;
  const float* src = W + (size_t)(r0 + r)*cols + c0 + cq;
  #pragma unroll
  for (int j = 0; j < 4; j++){
    float4 v = *(const float4*)(src + 4*j);
    us4 o; o.x = f2b(v.x); o.y = f2b(v.y); o.z = f2b(v.z); o.w = f2b(v.w);
    *(us4*)&T[r][cq + 4*j] = o;
  }
  __syncthreads();
  int c = t >> 2, rq = (t & 3) * 16;
  us8 o0, o1;
  #pragma unroll
  for (int j = 0; j < 8; j++){ o0[j] = T[rq + j][c]; o1[j] = T[rq + 8 + j][c]; }
  u16* dstp = WT + (size_t)(c0 + c)*rows + r0 + rq;
  *(us8*)dstp = o0;
  *(us8*)(dstp + 8) = o1;
}

// ============ pro: BN1 partials (nBn, f32x4, spread atomics into 64 sets) + wconv (32) + histogram (C) ============
__global__ __launch_bounds__(256) void k_pro(
    const float* __restrict__ Wq, const float* __restrict__ Wk, const float* __restrict__ Wv,
    const float* __restrict__ Wo, const float* __restrict__ W1, const float* __restrict__ W2,
    u16* __restrict__ wtq, u16* __restrict__ wtk, u16* __restrict__ wtv,
    u16* __restrict__ wto, u16* __restrict__ wt1, u16* __restrict__ wt2,
    const float* __restrict__ h, float* __restrict__ sets1,
    const int* __restrict__ dst, int* __restrict__ cntT,
    int nBn, int N, int E, int B, int C){
  __shared__ f32x4 lsS[256], lsQ[256];
  __shared__ int hist[256];
  int b = blockIdx.x, t = threadIdx.x;
  if (b < nBn){
    int qd = t & 31, rl = t >> 5;
    int r0 = b * 128;
    f32x4 s = {0.f,0.f,0.f,0.f}, sq = {0.f,0.f,0.f,0.f};
    for (int r = rl; r < 128; r += 8){
      int row = r0 + r;
      if (row < N){
        f32x4 v = *(const f32x4*)(h + (size_t)row*NDIM + qd*4);
        s += v; sq += v*v;
      }
    }
    lsS[t] = s; lsQ[t] = sq; __syncthreads();
    if (rl < 4){ lsS[t] += lsS[t+128]; lsQ[t] += lsQ[t+128]; } __syncthreads();
    if (rl < 2){ lsS[t] += lsS[t+64];  lsQ[t] += lsQ[t+64];  } __syncthreads();
    if (rl == 0){
      f32x4 S  = lsS[t] + lsS[t+32];
      f32x4 Qv = lsQ[t] + lsQ[t+32];
      float* sp = sets1 + ((size_t)(b & 63) << 8);
      atomicAdd(&sp[qd*4+0], S.x); atomicAdd(&sp[qd*4+1], S.y);
      atomicAdd(&sp[qd*4+2], S.z); atomicAdd(&sp[qd*4+3], S.w);
      atomicAdd(&sp[128+qd*4+0], Qv.x); atomicAdd(&sp[128+qd*4+1], Qv.y);
      atomicAdd(&sp[128+qd*4+2], Qv.z); atomicAdd(&sp[128+qd*4+3], Qv.w);
    }
    return;
  }
  b -= nBn;
  if (b < 16){
    const float* Ws[4] = {Wq, Wk, Wv, Wo};
    u16* Ts[4] = {wtq, wtk, wtv, wto};
    int wi = b >> 2, ti = b & 3;
    wconv_tile(Ws[wi], Ts[wi], 128, 128, ti >> 1, ti & 1, t);
    return;
  }
  if (b < 24){
    int ti = b - 16;
    wconv_tile(W1, wt1, 128, 256, ti >> 2, ti & 3, t);
    return;
  }
  if (b < 32){
    int ti = b - 24;
    wconv_tile(W2, wt2, 256, 128, ti & 3, ti >> 2, t);
    return;
  }
  int ci = b - 32;
  if (ci >= C) return;
  hist[t] = 0; __syncthreads();
  int e0 = ci * 4096;
  #pragma unroll
  for (int j = 0; j < 16; j++){
    int e = e0 + t + j*256;
    if (e < E) atomicAdd(&hist[dst[e] >> 8], 1);
  }
  __syncthreads();
  if (t < B) cntT[t*C + ci] = hist[t];
}

// deterministic partials reduce: acc[t] = sum_i part[i*256 + t]
__device__ __forceinline__ float reduce_part(const float* __restrict__ part, int nP, int t){
  float a0 = 0.f, a1 = 0.f, a2 = 0.f, a3 = 0.f;
  int i = 0;
  for (; i + 4 <= nP; i += 4){
    a0 += part[(size_t)(i+0)*256 + t];
    a1 += part[(size_t)(i+1)*256 + t];
    a2 += part[(size_t)(i+2)*256 + t];
    a3 += part[(size_t)(i+3)*256 + t];
  }
  for (; i < nP; i++) a0 += part[(size_t)i*256 + t];
  return (a0 + a1) + (a2 + a3);
}

// ============ block 0: BN1 reduce (64 sets) + finalize; blocks 1..: scan partials over cntT ============
__global__ __launch_bounds__(256) void k_bnf_scan(
    const float* __restrict__ sets1,
    const float* __restrict__ g, const float* __restrict__ b_,
    float* __restrict__ scsh, int N,
    const int* __restrict__ in, int* __restrict__ bsum, int len){
  __shared__ int ls[256];
  __shared__ float sm[256];
  int t = threadIdx.x, b = blockIdx.x;
  if (b == 0){
    sm[t] = reduce_part(sets1, 64, t);
    __syncthreads();
    if (t < 128){
      float mean = sm[t] / (float)N;
      float var  = sm[128+t] / (float)N - mean*mean;
      float rstd = rsqrtf(var + EPSV);
      float sc = g[t] * rstd;
      scsh[t] = sc; scsh[128+t] = b_[t] - mean*sc;
    }
    return;
  }
  b -= 1;
  int i = b*256 + t;
  ls[t] = (i < len) ? in[i] : 0; __syncthreads();
  for (int off = 128; off > 0; off >>= 1){
    if (t < off) ls[t] += ls[t + off];
    __syncthreads();
  }
  if (t == 0) bsum[b] = ls[0];
}

// ============ BN2 reduce (64 spread-atomic sets) + finalize ============
__global__ __launch_bounds__(256) void k_bn_final(const float* __restrict__ sets,
                                                  const float* __restrict__ g, const float* __restrict__ b,
                                                  float* __restrict__ scsh, int N){
  __shared__ float sm[256];
  int t = threadIdx.x;
  sm[t] = reduce_part(sets, 64, t);
  __syncthreads();
  if (t < 128){
    float mean = sm[t] / (float)N;
    float var  = sm[128+t] / (float)N - mean*mean;
    float rstd = rsqrtf(var + EPSV);
    float sc = g[t] * rstd;
    scsh[t] = sc; scsh[128+t] = b[t] - mean*sc;
  }
}

// ============ fused top-scan + down-sweep: each block recomputes the <=256-entry top scan from raw bsum ============
__global__ __launch_bounds__(256) void k_scan_down2(const int* __restrict__ in, const int* __restrict__ bsum,
                                                    int nb, int* __restrict__ outp,
                                                    int* __restrict__ rowptr, int len, int N, int E){
  __shared__ int ls[256], top[256];
  int t = threadIdx.x, b = blockIdx.x;
  int tv = (t < nb) ? bsum[t] : 0;
  top[t] = tv; __syncthreads();
  for (int off = 1; off < 256; off <<= 1){
    int add = (t >= off) ? top[t - off] : 0;
    __syncthreads();
    top[t] += add;
    __syncthreads();
  }
  int base = (b > 0) ? top[b - 1] : 0;
  int i = b*256 + t;
  int v = (i < len) ? in[i] : 0;
  ls[t] = v; __syncthreads();
  for (int off = 1; off < 256; off <<= 1){
    int add = (t >= off) ? ls[t - off] : 0;
    __syncthreads();
    ls[t] += add;
    __syncthreads();
  }
  if (i < len) outp[i] = ls[t] - v + base;
  if (b == 0 && t == 0) rowptr[N] = E;
}

// ============ fine sort within bucket (1024 threads): rowptr + csr_src (LDS atomics only) ============
__global__ __launch_bounds__(1024) void k_finesort(const int2* __restrict__ ebuf, const int* __restrict__ scn,
                                                   int* __restrict__ rowptr, int* __restrict__ csr_src,
                                                   int B, int C, int N, int E){
  __shared__ int ls[256], cur[256];
  int b = blockIdx.x, t = threadIdx.x;
  int base = scn[b*C];
  int end  = (b == B-1) ? E : scn[(b+1)*C];
  int lo = b << 8;
  if (t < 256) cur[t] = 0;
  __syncthreads();
  for (int e = base + t; e < end; e += 1024) atomicAdd(&cur[ebuf[e].x - lo], 1);
  __syncthreads();
  int cnt_t = 0;
  if (t < 256){ cnt_t = cur[t]; ls[t] = cnt_t; }
  __syncthreads();
  for (int off = 1; off < 256; off <<= 1){
    int add = 0;
    if (t < 256 && t >= off) add = ls[t - off];
    __syncthreads();
    if (t < 256) ls[t] += add;
    __syncthreads();
  }
  int excl_t = 0;
  if (t < 256){
    excl_t = ls[t] - cnt_t;
    if (lo + t < N) rowptr[lo + t] = base + excl_t;
  }
  __syncthreads();
  if (t < 256) cur[t] = excl_t;
  __syncthreads();
  for (int e = base + t; e < end; e += 1024){
    int2 p = ebuf[e];
    int slot = base + atomicAdd(&cur[p.x - lo], 1);
    csr_src[slot] = p.y;
  }
}

// ============ merged: bucket pass (first C blocks) + BN1-apply + QKV projection (MFMA, 32-row tiles) ============
__global__ __launch_bounds__(256) void k_qkv_bucket(
    const float* __restrict__ h, const float* __restrict__ scsh,
    const u16* __restrict__ WTq, const u16* __restrict__ WTk, const u16* __restrict__ WTv,
    u16* __restrict__ Q, u16* __restrict__ K, u16* __restrict__ V, int N,
    const int* __restrict__ src, const int* __restrict__ dst,
    const int* __restrict__ scn, int2* __restrict__ ebuf, int B, int C, int E){
  __shared__ u16 hn[32][136];
  __shared__ u16 ob[32][136];
  __shared__ int off[256];
  int b = blockIdx.x, t = threadIdx.x;
  if (b < C){
    off[t] = (t < B) ? scn[t*C + b] : 0;
    __syncthreads();
    int e0 = b * 4096;
    #pragma unroll
    for (int j = 0; j < 16; j++){
      int e = e0 + t + j*256;
      if (e < E){
        int d = dst[e], s = src[e];
        int slot = atomicAdd(&off[d >> 8], 1);
        ebuf[slot] = make_int2(d, s);
      }
    }
    return;
  }
  int r0 = (b - C) * 32;
  int row = t >> 3, c0 = (t & 7) * 16;
  {
    int rr = r0 + row;
    #pragma unroll
    for (int j = 0; j < 4; j++){
      int c = c0 + 4*j;
      float4 v = make_float4(0.f,0.f,0.f,0.f);
      if (rr < N) v = *(const float4*)(h + (size_t)rr*NDIM + c);
      us4 o;
      o.x = f2b(v.x * scsh[c]   + scsh[128+c]);
      o.y = f2b(v.y * scsh[c+1] + scsh[129+c]);
      o.z = f2b(v.z * scsh[c+2] + scsh[130+c]);
      o.w = f2b(v.w * scsh[c+3] + scsh[131+c]);
      *(us4*)&hn[row][c] = o;
    }
  }
  __syncthreads();
  int lane = t & 63, w = t >> 6;
  int lr = lane & 15, kg = lane >> 4;
  f32x4 zero = {0.f,0.f,0.f,0.f};

  #define DO_PASS(WT, OUT, FIRST) { \
    f32x4 acc[2][2]; \
    _Pragma("unroll") for (int n = 0; n < 2; n++) _Pragma("unroll") for (int m = 0; m < 2; m++) acc[n][m] = zero; \
    gemm_tiles<2,2,4,128,136>(&hn[0][0], WT, lr, kg, w*32, acc); \
    if (!FIRST) __syncthreads(); \
    _Pragma("unroll") for (int n = 0; n < 2; n++){ \
      int col = w*32 + n*16 + lr; \
      _Pragma("unroll") for (int m = 0; m < 2; m++) \
        _Pragma("unroll") for (int r = 0; r < 4; r++) \
          ob[m*16 + kg*4 + r][col] = f2b(acc[n][m][r]); \
    } \
    __syncthreads(); \
    if (r0 + row < N){ \
      u16* dp = OUT + (size_t)(r0 + row)*NDIM + c0; \
      *(us8*)dp       = *(const us8*)&ob[row][c0]; \
      *(us8*)(dp + 8) = *(const us8*)&ob[row][c0 + 8]; \
    } }

  DO_PASS(WTq, Q, true)

  // K pass: GEMM -> ob(bf16) -> fp8 (or bf16 fallback) coalesced store
  {
    f32x4 acc[2][2];
    #pragma unroll
    for (int n = 0; n < 2; n++)
      #pragma unroll
      for (int m = 0; m < 2; m++) acc[n][m] = zero;
    gemm_tiles<2,2,4,128,136>(&hn[0][0], WTk, lr, kg, w*32, acc);
    __syncthreads();
    #pragma unroll
    for (int n = 0; n < 2; n++){
      int col = w*32 + n*16 + lr;
      #pragma unroll
      for (int m = 0; m < 2; m++)
        #pragma unroll
        for (int r = 0; r < 4; r++)
          ob[m*16 + kg*4 + r][col] = f2b(acc[n][m][r]);
    }
    __syncthreads();
    if (r0 + row < N){
#if HAVE_FP8
      u8* dp = (u8*)K + (size_t)(r0 + row)*NDIM + c0;
      unsigned wd[4];
      #pragma unroll
      for (int j = 0; j < 2; j++){
        us8 v = *(const us8*)&ob[row][c0 + 8*j];
        int w0 = __builtin_amdgcn_cvt_pk_fp8_f32(b2f(v[0]), b2f(v[1]), 0, false);
        w0     = __builtin_amdgcn_cvt_pk_fp8_f32(b2f(v[2]), b2f(v[3]), w0, true);
        int w1 = __builtin_amdgcn_cvt_pk_fp8_f32(b2f(v[4]), b2f(v[5]), 0, false);
        w1     = __builtin_amdgcn_cvt_pk_fp8_f32(b2f(v[6]), b2f(v[7]), w1, true);
        wd[2*j] = (unsigned)w0; wd[2*j+1] = (unsigned)w1;
      }
      *(uint4*)dp = make_uint4(wd[0], wd[1], wd[2], wd[3]);
#else
      u16* dp = K + (size_t)(r0 + row)*NDIM + c0;
      *(us8*)dp       = *(const us8*)&ob[row][c0];
      *(us8*)(dp + 8) = *(const us8*)&ob[row][c0 + 8];
#endif
    }
  }

  DO_PASS(WTv, V, false)
  #undef DO_PASS
}

// ============ fused edge phase: score + softmax + weighted V aggregation ============
// Depth-2 software pipeline; fp8 K gather (128 B/edge); bf16 V gather (256 B/edge).
__global__ __launch_bounds__(256) void k_sagg(const int* __restrict__ rowptr, const int* __restrict__ csr_src,
                                              const u16* __restrict__ Q, const u16* __restrict__ K,
                                              const u16* __restrict__ V, u16* __restrict__ wV, int N){
  __shared__ float wx[4][64];
  int w = threadIdx.x >> 6, l = threadIdx.x & 63;
  int n = blockIdx.x*4 + w;
  if (n >= N) return;
  int j8 = l >> 3, hh = l & 7, d0 = l * 2;

  f32x2 qf[8];
  {
    const unsigned* qp = (const unsigned*)(Q + (size_t)n*NDIM + hh*16);
    #pragma unroll
    for (int t = 0; t < 8; t++){
      unsigned u = qp[t];
      qf[t].x = blo(u) * 0.25f;
      qf[t].y = bhi(u) * 0.25f;
    }
  }

  int e0 = rowptr[n], e1 = rowptr[n+1];
  int i0 = __builtin_amdgcn_readfirstlane(e0);
  int deg = e1 - e0;
  int nw  = deg >> 3;
  int rem = deg & 7;

  float ssum_l = 0.f;
  f32x2 a01 = {0.f, 0.f};

#if HAVE_FP8
  const u8* Kb = (const u8*)K;
  uint4 kA, kB;
  #define KLOAD(dst_, sidx) dst_ = *(const uint4*)(Kb + (size_t)(sidx)*NDIM + (hh << 4));
  #define KDOTP(p, kk) { \
    f32x2 p2 = {0.f, 0.f}; \
    p2 += qf[0] * __builtin_amdgcn_cvt_pk_f32_fp8((int)kk.x, false); \
    p2 += qf[1] * __builtin_amdgcn_cvt_pk_f32_fp8((int)kk.x, true); \
    p2 += qf[2] * __builtin_amdgcn_cvt_pk_f32_fp8((int)kk.y, false); \
    p2 += qf[3] * __builtin_amdgcn_cvt_pk_f32_fp8((int)kk.y, true); \
    p2 += qf[4] * __builtin_amdgcn_cvt_pk_f32_fp8((int)kk.z, false); \
    p2 += qf[5] * __builtin_amdgcn_cvt_pk_f32_fp8((int)kk.z, true); \
    p2 += qf[6] * __builtin_amdgcn_cvt_pk_f32_fp8((int)kk.w, false); \
    p2 += qf[7] * __builtin_amdgcn_cvt_pk_f32_fp8((int)kk.w, true); \
    p = p2.x + p2.y; }
#else
  struct krow { uint4 lo, hi; };
  krow kA, kB;
  #define KLOAD(dst_, sidx) { \
    const uint4* kp_ = (const uint4*)(K + (size_t)(sidx)*NDIM + hh*16); \
    dst_.lo = kp_[0]; dst_.hi = kp_[1]; }
  #define KDOTP(p, kk) { \
    f32x2 p2 = {0.f, 0.f}; \
    p2 += qf[0] * b2f2(kk.lo.x); p2 += qf[1] * b2f2(kk.lo.y); \
    p2 += qf[2] * b2f2(kk.lo.z); p2 += qf[3] * b2f2(kk.lo.w); \
    p2 += qf[4] * b2f2(kk.hi.x); p2 += qf[5] * b2f2(kk.hi.y); \
    p2 += qf[6] * b2f2(kk.hi.z); p2 += qf[7] * b2f2(kk.hi.w); \
    p = p2.x + p2.y; }
#endif

  unsigned vvA[8], vvB[8];

  if (nw >= 1){
    int s0=csr_src[i0+0], s1=csr_src[i0+1], s2=csr_src[i0+2], s3=csr_src[i0+3];
    int s4=csr_src[i0+4], s5=csr_src[i0+5], s6=csr_src[i0+6], s7=csr_src[i0+7];
    vvA[0] = *(const unsigned*)(V + (size_t)s0*NDIM + d0);
    vvA[1] = *(const unsigned*)(V + (size_t)s1*NDIM + d0);
    vvA[2] = *(const unsigned*)(V + (size_t)s2*NDIM + d0);
    vvA[3] = *(const unsigned*)(V + (size_t)s3*NDIM + d0);
    vvA[4] = *(const unsigned*)(V + (size_t)s4*NDIM + d0);
    vvA[5] = *(const unsigned*)(V + (size_t)s5*NDIM + d0);
    vvA[6] = *(const unsigned*)(V + (size_t)s6*NDIM + d0);
    vvA[7] = *(const unsigned*)(V + (size_t)s7*NDIM + d0);
    int sidx = csr_src[e0 + j8];
    KLOAD(kA, sidx)
  }

  for (int wi = 0; wi < nw; wi++){
    if (wi + 1 < nw){
      int ib = i0 + wi*8 + 8;
      int s0=csr_src[ib+0], s1=csr_src[ib+1], s2=csr_src[ib+2], s3=csr_src[ib+3];
      int s4=csr_src[ib+4], s5=csr_src[ib+5], s6=csr_src[ib+6], s7=csr_src[ib+7];
      vvB[0] = *(const unsigned*)(V + (size_t)s0*NDIM + d0);
      vvB[1] = *(const unsigned*)(V + (size_t)s1*NDIM + d0);
      vvB[2] = *(const unsigned*)(V + (size_t)s2*NDIM + d0);
      vvB[3] = *(const unsigned*)(V + (size_t)s3*NDIM + d0);
      vvB[4] = *(const unsigned*)(V + (size_t)s4*NDIM + d0);
      vvB[5] = *(const unsigned*)(V + (size_t)s5*NDIM + d0);
      vvB[6] = *(const unsigned*)(V + (size_t)s6*NDIM + d0);
      vvB[7] = *(const unsigned*)(V + (size_t)s7*NDIM + d0);
      int sidx = csr_src[e0 + wi*8 + 8 + j8];
      KLOAD(kB, sidx)
    }
    float p;
    KDOTP(p, kA)
    p = fminf(5.f, fmaxf(-5.f, p));
    float wgt = __expf(p);
    ssum_l += wgt;
    wx[w][hh*8 + j8] = wgt;
    float4 wa = *(const float4*)&wx[w][j8*8];
    float4 wb = *(const float4*)&wx[w][j8*8 + 4];
    a01 += b2f2(vvA[0]) * wa.x;
    a01 += b2f2(vvA[1]) * wa.y;
    a01 += b2f2(vvA[2]) * wa.z;
    a01 += b2f2(vvA[3]) * wa.w;
    a01 += b2f2(vvA[4]) * wb.x;
    a01 += b2f2(vvA[5]) * wb.y;
    a01 += b2f2(vvA[6]) * wb.z;
    a01 += b2f2(vvA[7]) * wb.w;
    if (wi + 1 < nw){
      #pragma unroll
      for (int j = 0; j < 8; j++) vvA[j] = vvB[j];
      kA = kB;
    }
  }

  if (rem > 0){
    int i0t = i0 + nw*8;
    int s[8];
    #pragma unroll
    for (int j = 0; j < 8; j++) s[j] = csr_src[i0t + (j < rem ? j : 0)];
    unsigned vv[8];
    #pragma unroll
    for (int j = 0; j < 8; j++) vv[j] = *(const unsigned*)(V + (size_t)s[j]*NDIM + d0);
    int sidx = csr_src[i0t + (j8 < rem ? j8 : 0)];
#if HAVE_FP8
    uint4 kT;
#else
    krow kT;
#endif
    KLOAD(kT, sidx)
    float p;
    KDOTP(p, kT)
    p = fminf(5.f, fmaxf(-5.f, p));
    float wgt = (j8 < rem) ? __expf(p) : 0.f;
    ssum_l += wgt;
    wx[w][hh*8 + j8] = wgt;
    float4 wa = *(const float4*)&wx[w][j8*8];
    float4 wb = *(const float4*)&wx[w][j8*8 + 4];
    a01 += b2f2(vv[0]) * wa.x;
    a01 += b2f2(vv[1]) * wa.y;
    a01 += b2f2(vv[2]) * wa.z;
    a01 += b2f2(vv[3]) * wa.w;
    a01 += b2f2(vv[4]) * wb.x;
    a01 += b2f2(vv[5]) * wb.y;
    a01 += b2f2(vv[6]) * wb.z;
    a01 += b2f2(vv[7]) * wb.w;
  }
  #undef KLOAD
  #undef KDOTP

  ssum_l += __shfl_xor(ssum_l, 8);
  ssum_l += __shfl_xor(ssum_l, 16);
  ssum_l += __shfl_xor(ssum_l, 32);
  float ssum = __shfl(ssum_l, j8);
  float inv = (e1 > e0) ? 1.f/ssum : 0.f;
  unsigned pk = (unsigned)f2b(a01.x*inv) | (((unsigned)f2b(a01.y*inv)) << 16);
  *(unsigned*)(wV + (size_t)n*NDIM + d0) = pk;
}

// ============ O-projection + residual + BN2 partials (spread atomics, 64 sets) ============
__global__ __launch_bounds__(256) void k_h2(const u16* __restrict__ wV, const u16* __restrict__ WTo,
                                            const float* __restrict__ bo, const float* __restrict__ h,
                                            float* __restrict__ h2, float* __restrict__ sets, int N){
  __shared__ u16 tw[32][136];
  __shared__ float ob[32][132];
  int t = threadIdx.x; int r0 = blockIdx.x * 32;
  int row = t >> 3, c0 = (t & 7) * 16;
  {
    int rr = r0 + row;
    us8 z = {0,0,0,0,0,0,0,0};
    const u16* sp = wV + (size_t)rr*NDIM + c0;
    *(us8*)&tw[row][c0]     = (rr < N) ? *(const us8*)sp       : z;
    *(us8*)&tw[row][c0 + 8] = (rr < N) ? *(const us8*)(sp + 8) : z;
  }
  __syncthreads();
  int lane = t & 63, w = t >> 6;
  int lr = lane & 15, kg = lane >> 4;
  f32x4 zero = {0.f,0.f,0.f,0.f};
  f32x4 acc[2][2];
  #pragma unroll
  for (int n = 0; n < 2; n++)
    #pragma unroll
    for (int m = 0; m < 2; m++) acc[n][m] = zero;
  gemm_tiles<2,2,4,128,136>(&tw[0][0], WTo, lr, kg, w*32, acc);
  #pragma unroll
  for (int n = 0; n < 2; n++){
    int col = w*32 + n*16 + lr;
    float bb = bo[col];
    #pragma unroll
    for (int m = 0; m < 2; m++)
      #pragma unroll
      for (int r = 0; r < 4; r++)
        ob[m*16 + kg*4 + r][col] = acc[n][m][r] + bb;
  }
  __syncthreads();
  if (r0 + row < N){
    const float* hp = h  + (size_t)(r0 + row)*NDIM + c0;
    float*       op = h2 + (size_t)(r0 + row)*NDIM + c0;
    #pragma unroll
    for (int j = 0; j < 4; j++){
      float4 hv = *(const float4*)(hp + 4*j);
      float4 o;
      o.x = ob[row][c0 + 4*j]     + hv.x;
      o.y = ob[row][c0 + 4*j + 1] + hv.y;
      o.z = ob[row][c0 + 4*j + 2] + hv.z;
      o.w = ob[row][c0 + 4*j + 3] + hv.w;
      *(float4*)(op + 4*j) = o;
      ob[row][c0 + 4*j]     = o.x;
      ob[row][c0 + 4*j + 1] = o.y;
      ob[row][c0 + 4*j + 2] = o.z;
      ob[row][c0 + 4*j + 3] = o.w;
    }
  } else {
    #pragma unroll
    for (int j = 0; j < 16; j++) ob[row][c0 + j] = 0.f;
  }
  __syncthreads();
  int colx = t & 127, hf = t >> 7;
  float s = 0.f, q = 0.f;
  #pragma unroll
  for (int r = 0; r < 16; r++){ float v = ob[hf*16 + r][colx]; s += v; q += v*v; }
  float* cs = (float*)&tw[0][0];
  cs[hf*256 + colx]       = s;
  cs[hf*256 + 128 + colx] = q;
  __syncthreads();
  if (t < 128){
    float* sp = sets + ((size_t)(blockIdx.x & 63) << 8);
    atomicAdd(&sp[t],       cs[t]       + cs[256 + t]);
    atomicAdd(&sp[128 + t], cs[128 + t] + cs[384 + t]);
  }
}

// ============ BN2-apply + FFN + residual (MFMA, 32-row tiles, coalesced epilogue) ============
__global__ __launch_bounds__(256) void k_ffn(const float* __restrict__ h2, const float* __restrict__ scsh,
                                             const u16* __restrict__ WT1, const float* __restrict__ b1,
                                             const u16* __restrict__ WT2, const float* __restrict__ b2,
                                             float* __restrict__ out, int N){
  __shared__ u16 x[32][136];
  __shared__ u16 tt[32][264];          // reused as float [32][132] after GEMM2
  int t = threadIdx.x; int r0 = blockIdx.x * 32;
  int row = t >> 3, c0 = (t & 7) * 16;
  {
    int rr = r0 + row;
    #pragma unroll
    for (int j = 0; j < 4; j++){
      int c = c0 + 4*j;
      float4 v = make_float4(0.f,0.f,0.f,0.f);
      if (rr < N) v = *(const float4*)(h2 + (size_t)rr*NDIM + c);
      us4 o;
      o.x = f2b(v.x * scsh[c]   + scsh[128+c]);
      o.y = f2b(v.y * scsh[c+1] + scsh[129+c]);
      o.z = f2b(v.z * scsh[c+2] + scsh[130+c]);
      o.w = f2b(v.w * scsh[c+3] + scsh[131+c]);
      *(us4*)&x[row][c] = o;
    }
  }
  __syncthreads();
  int lane = t & 63, w = t >> 6;
  int lr = lane & 15, kg = lane >> 4;
  f32x4 zero = {0.f,0.f,0.f,0.f};
  {
    f32x4 a1[4][2];
    #pragma unroll
    for (int n = 0; n < 4; n++)
      #pragma unroll
      for (int m = 0; m < 2; m++) a1[n][m] = zero;
    gemm_tiles<4,2,4,128,136>(&x[0][0], WT1, lr, kg, w*64, a1);
    #pragma unroll
    for (int n = 0; n < 4; n++){
      int col = w*64 + n*16 + lr;
      float bb = b1[col];
      #pragma unroll
      for (int m = 0; m < 2; m++)
        #pragma unroll
        for (int r = 0; r < 4; r++)
          tt[m*16 + kg*4 + r][col] = f2b(fmaxf(a1[n][m][r] + bb, 0.f));
    }
  }
  __syncthreads();
  f32x4 a2[2][2];
  #pragma unroll
  for (int n = 0; n < 2; n++)
    #pragma unroll
    for (int m = 0; m < 2; m++) a2[n][m] = zero;
  gemm_tiles<2,2,8,256,264>(&tt[0][0], WT2, lr, kg, w*32, a2);
  __syncthreads();
  float* ob2 = (float*)&tt[0][0];       // [32][132] overlay
  #pragma unroll
  for (int n = 0; n < 2; n++){
    int col = w*32 + n*16 + lr;
    float bb = b2[col];
    #pragma unroll
    for (int m = 0; m < 2; m++)
      #pragma unroll
      for (int r = 0; r < 4; r++)
        ob2[(m*16 + kg*4 + r)*132 + col] = a2[n][m][r] + bb;
  }
  __syncthreads();
  if (r0 + row < N){
    const float* hp = h2  + (size_t)(r0 + row)*NDIM + c0;
    float*       op = out + (size_t)(r0 + row)*NDIM + c0;
    #pragma unroll
    for (int j = 0; j < 4; j++){
      float4 hv = *(const float4*)(hp + 4*j);
      float4 o;
      o.x = ob2[row*132 + c0 + 4*j]     + hv.x;
      o.y = ob2[row*132 + c0 + 4*j + 1] + hv.y;
      o.z = ob2[row*132 + c0 + 4*j + 2] + hv.z;
      o.w = ob2[row*132 + c0 + 4*j + 3] + hv.w;
      *(float4*)(op + 4*j) = o;
    }
  }
}

extern "C" void kernel_launch(void* const* d_in, const int* in_sizes, int n_in,
                              void* d_out, int out_size, void* d_ws, size_t ws_size,
                              hipStream_t stream) {
  const float* h    = (const float*)d_in[0];
  const int*   src  = (const int*)d_in[1];
  const int*   dst  = (const int*)d_in[2];
  const float* Wq   = (const float*)d_in[3];
  const float* Wk   = (const float*)d_in[4];
  const float* Wv   = (const float*)d_in[5];
  const float* Wo   = (const float*)d_in[6];
  const float* bo   = (const float*)d_in[7];
  const float* bn1g = (const float*)d_in[8];
  const float* bn1b = (const float*)d_in[9];
  const float* bn2g = (const float*)d_in[10];
  const float* bn2b = (const float*)d_in[11];
  const float* W1   = (const float*)d_in[12];
  const float* b1   = (const float*)d_in[13];
  const float* W2   = (const float*)d_in[14];
  const float* b2   = (const float*)d_in[15];
  float* out = (float*)d_out;

  int N = in_sizes[0] / NDIM;
  int E = in_sizes[1];
  size_t fN = (size_t)N * NDIM;

  int B   = (N + 255) >> 8;       // coarse buckets (256 nodes each), <= 256
  int C   = (E + 4095) >> 12;     // edge chunks (4096 edges each)
  int NB2 = B * C;
  int nb2 = (NB2 + 255) / 256;    // <= 256
  int nBn = (N + 127) / 128;
  int n32 = (N + 31) / 32;

  u16* Q  = (u16*)d_ws;
  u16* K  = Q + fN;               // fp8 path uses first fN BYTES of this 2*fN-byte slot
  u16* V  = K + fN;
  u16* wV = Q;                    // reuse: each wave reads Q[n] before writing wV[n]
  float* h2   = (float*)(V + fN);
  int2* ebuf  = (int2*)(h2 + fN);
  int* rowptr = (int*)(ebuf + E);
  int* bsum   = rowptr + (N + 1);
  int* cntT   = bsum + 256;
  int* scn    = cntT + NB2;
  int* csr_src= scn + NB2;
  float* sets1 = (float*)(csr_src + E);       // 64*256
  float* sets2 = sets1 + 64*256;              // 64*256
  float* scsh1 = sets2 + 64*256;              // 256
  float* scsh2 = scsh1 + 256;                 // 256
  u16* wtq = (u16*)(scsh2 + 256);
  u16* wtk = wtq + NDIM*NDIM;
  u16* wtv = wtk + NDIM*NDIM;
  u16* wto = wtv + NDIM*NDIM;
  u16* wt1 = wto + NDIM*NDIM;
  u16* wt2 = wt1 + NDIM*2*NDIM;

  hipMemsetAsync(sets1, 0, 2*64*256*sizeof(float), stream);

  k_pro<<<nBn + 32 + C, 256, 0, stream>>>(Wq, Wk, Wv, Wo, W1, W2,
                                          wtq, wtk, wtv, wto, wt1, wt2,
                                          h, sets1, dst, cntT, nBn, N, E, B, C);
  k_bnf_scan<<<1 + nb2, 256, 0, stream>>>(sets1, bn1g, bn1b, scsh1, N, cntT, bsum, NB2);
  k_scan_down2<<<nb2, 256, 0, stream>>>(cntT, bsum, nb2, scn, rowptr, NB2, N, E);

  k_qkv_bucket<<<C + n32, 256, 0, stream>>>(h, scsh1, wtq, wtk, wtv, Q, K, V, N,
                                            src, dst, scn, ebuf, B, C, E);
  k_finesort<<<B, 1024, 0, stream>>>(ebuf, scn, rowptr, csr_src, B, C, N, E);

  k_sagg<<<(N + 3)/4, 256, 0, stream>>>(rowptr, csr_src, Q, K, V, wV, N);

  k_h2<<<n32, 256, 0, stream>>>(wV, wto, bo, h, h2, sets2, N);
  k_bn_final<<<1, 256, 0, stream>>>(sets2, bn2g, bn2b, scsh2, N);
  k_ffn<<<n32, 256, 0, stream>>>(h2, scsh2, wt1, b1, wt2, b2, out, N);
}

// Round 18
// 175.871 us; speedup vs baseline: 1.4042x; 1.0011x over previous
//
#include <hip/hip_runtime.h>
#include <hip/hip_bf16.h>

#define NDIM 128
#define NHEAD 8
#define EPSV 1e-5f

#if defined(__has_builtin)
#  if __has_builtin(__builtin_amdgcn_cvt_pk_fp8_f32) && __has_builtin(__builtin_amdgcn_cvt_pk_f32_fp8)
#    define HAVE_FP8 1
#  else
#    define HAVE_FP8 0
#  endif
#else
#  define HAVE_FP8 0
#endif

typedef unsigned short u16;
typedef unsigned char u8;
using bf16x8 = __attribute__((ext_vector_type(8))) short;
using f32x4  = __attribute__((ext_vector_type(4))) float;
using f32x2  = __attribute__((ext_vector_type(2))) float;
using us8    = __attribute__((ext_vector_type(8))) unsigned short;
using us4    = __attribute__((ext_vector_type(4))) unsigned short;

__device__ __forceinline__ u16 f2b(float x){
  union { float f; unsigned u; } v; v.f = x;
  unsigned r = v.u + 0x7FFFu + ((v.u >> 16) & 1u);
  return (u16)(r >> 16);
}
__device__ __forceinline__ float b2f(u16 u){
  union { unsigned u; float f; } v; v.u = ((unsigned)u) << 16; return v.f;
}
__device__ __forceinline__ float blo(unsigned u){
  union { unsigned u; float f; } v; v.u = u << 16; return v.f;
}
__device__ __forceinline__ float bhi(unsigned u){
  union { unsigned u; float f; } v; v.u = u & 0xFFFF0000u; return v.f;
}
__device__ __forceinline__ f32x2 b2f2(unsigned u){
  f32x2 r; r.x = blo(u); r.y = bhi(u); return r;
}

// A-frag: lane provides A[lane%16][(lane/16)*8 + j]; B-frag: B[(lane/16)*8+j][lane%16]
// C/D: col = lane&15, row = (lane>>4)*4 + reg   (measured m89)
template<int NT, int MT, int KS, int WTLD, int XSTR>
__device__ __forceinline__ void gemm_tiles(const u16* X, const u16* __restrict__ WT,
                                           int lr, int kg, int colbase, f32x4 (&acc)[NT][MT]){
  #pragma unroll
  for (int ks = 0; ks < KS; ks++){
    bf16x8 a[MT];
    #pragma unroll
    for (int m = 0; m < MT; m++)
      a[m] = *(const bf16x8*)(X + (size_t)(m*16 + lr)*XSTR + ks*32 + kg*8);
    #pragma unroll
    for (int n = 0; n < NT; n++){
      int col = colbase + n*16 + lr;
      bf16x8 b = *(const bf16x8*)(WT + (size_t)col*WTLD + ks*32 + kg*8);
      #pragma unroll
      for (int m = 0; m < MT; m++)
        acc[n][m] = __builtin_amdgcn_mfma_f32_16x16x32_bf16(a[m], b, acc[n][m], 0, 0, 0);
    }
  }
}

// transpose one 64x64 tile of W (rows x cols, f32) into WT (cols x rows, bf16)
__device__ __forceinline__ void wconv_tile(const float* __restrict__ W, u16* __restrict__ WT,
                                           int rows, int cols, int tr, int tc, int t){
  __shared__ u16 T[64][66];
  int r0 = tr*64, c0 = tc*64;
  int r = t >> 2, cq = (t & 3) * 16;
  const float* src = W + (size_t)(r0 + r)*cols + c0 + cq;
  #pragma unroll
  for (int j = 0; j < 4; j++){
    float4 v = *(const float4*)(src + 4*j);
    us4 o; o.x = f2b(v.x); o.y = f2b(v.y); o.z = f2b(v.z); o.w = f2b(v.w);
    *(us4*)&T[r][cq + 4*j] = o;
  }
  __syncthreads();
  int c = t >> 2, rq = (t & 3) * 16;
  us8 o0, o1;
  #pragma unroll
  for (int j = 0; j < 8; j++){ o0[j] = T[rq + j][c]; o1[j] = T[rq + 8 + j][c]; }
  u16* dstp = WT + (size_t)(c0 + c)*rows + r0 + rq;
  *(us8*)dstp = o0;
  *(us8*)(dstp + 8) = o1;
}

// ============ pro: BN1 partials (nBn, f32x4, spread atomics into 64 sets) + wconv (32) + histogram (C) ============
__global__ __launch_bounds__(256) void k_pro(
    const float* __restrict__ Wq, const float* __restrict__ Wk, const float* __restrict__ Wv,
    const float* __restrict__ Wo, const float* __restrict__ W1, const float* __restrict__ W2,
    u16* __restrict__ wtq, u16* __restrict__ wtk, u16* __restrict__ wtv,
    u16* __restrict__ wto, u16* __restrict__ wt1, u16* __restrict__ wt2,
    const float* __restrict__ h, float* __restrict__ sets1,
    const int* __restrict__ dst, int* __restrict__ cntT,
    int nBn, int N, int E, int B, int C){
  __shared__ f32x4 lsS[256], lsQ[256];
  __shared__ int hist[256];
  int b = blockIdx.x, t = threadIdx.x;
  if (b < nBn){
    int qd = t & 31, rl = t >> 5;
    int r0 = b * 128;
    f32x4 s = {0.f,0.f,0.f,0.f}, sq = {0.f,0.f,0.f,0.f};
    for (int r = rl; r < 128; r += 8){
      int row = r0 + r;
      if (row < N){
        f32x4 v = *(const f32x4*)(h + (size_t)row*NDIM + qd*4);
        s += v; sq += v*v;
      }
    }
    lsS[t] = s; lsQ[t] = sq; __syncthreads();
    if (rl < 4){ lsS[t] += lsS[t+128]; lsQ[t] += lsQ[t+128]; } __syncthreads();
    if (rl < 2){ lsS[t] += lsS[t+64];  lsQ[t] += lsQ[t+64];  } __syncthreads();
    if (rl == 0){
      f32x4 S  = lsS[t] + lsS[t+32];
      f32x4 Qv = lsQ[t] + lsQ[t+32];
      float* sp = sets1 + ((size_t)(b & 63) << 8);
      atomicAdd(&sp[qd*4+0], S.x); atomicAdd(&sp[qd*4+1], S.y);
      atomicAdd(&sp[qd*4+2], S.z); atomicAdd(&sp[qd*4+3], S.w);
      atomicAdd(&sp[128+qd*4+0], Qv.x); atomicAdd(&sp[128+qd*4+1], Qv.y);
      atomicAdd(&sp[128+qd*4+2], Qv.z); atomicAdd(&sp[128+qd*4+3], Qv.w);
    }
    return;
  }
  b -= nBn;
  if (b < 16){
    const float* Ws[4] = {Wq, Wk, Wv, Wo};
    u16* Ts[4] = {wtq, wtk, wtv, wto};
    int wi = b >> 2, ti = b & 3;
    wconv_tile(Ws[wi], Ts[wi], 128, 128, ti >> 1, ti & 1, t);
    return;
  }
  if (b < 24){
    int ti = b - 16;
    wconv_tile(W1, wt1, 128, 256, ti >> 2, ti & 3, t);
    return;
  }
  if (b < 32){
    int ti = b - 24;
    wconv_tile(W2, wt2, 256, 128, ti & 3, ti >> 2, t);
    return;
  }
  int ci = b - 32;
  if (ci >= C) return;
  hist[t] = 0; __syncthreads();
  int e0 = ci * 4096;
  #pragma unroll
  for (int j = 0; j < 16; j++){
    int e = e0 + t + j*256;
    if (e < E) atomicAdd(&hist[dst[e] >> 8], 1);
  }
  __syncthreads();
  if (t < B) cntT[t*C + ci] = hist[t];
}

// deterministic partials reduce: acc[t] = sum_i part[i*256 + t]
__device__ __forceinline__ float reduce_part(const float* __restrict__ part, int nP, int t){
  float a0 = 0.f, a1 = 0.f, a2 = 0.f, a3 = 0.f;
  int i = 0;
  for (; i + 4 <= nP; i += 4){
    a0 += part[(size_t)(i+0)*256 + t];
    a1 += part[(size_t)(i+1)*256 + t];
    a2 += part[(size_t)(i+2)*256 + t];
    a3 += part[(size_t)(i+3)*256 + t];
  }
  for (; i < nP; i++) a0 += part[(size_t)i*256 + t];
  return (a0 + a1) + (a2 + a3);
}

// ============ block 0: BN1 reduce (64 sets) + finalize; blocks 1..: scan partials over cntT ============
__global__ __launch_bounds__(256) void k_bnf_scan(
    const float* __restrict__ sets1,
    const float* __restrict__ g, const float* __restrict__ b_,
    float* __restrict__ scsh, int N,
    const int* __restrict__ in, int* __restrict__ bsum, int len){
  __shared__ int ls[256];
  __shared__ float sm[256];
  int t = threadIdx.x, b = blockIdx.x;
  if (b == 0){
    sm[t] = reduce_part(sets1, 64, t);
    __syncthreads();
    if (t < 128){
      float mean = sm[t] / (float)N;
      float var  = sm[128+t] / (float)N - mean*mean;
      float rstd = rsqrtf(var + EPSV);
      float sc = g[t] * rstd;
      scsh[t] = sc; scsh[128+t] = b_[t] - mean*sc;
    }
    return;
  }
  b -= 1;
  int i = b*256 + t;
  ls[t] = (i < len) ? in[i] : 0; __syncthreads();
  for (int off = 128; off > 0; off >>= 1){
    if (t < off) ls[t] += ls[t + off];
    __syncthreads();
  }
  if (t == 0) bsum[b] = ls[0];
}

// ============ BN2 reduce (64 spread-atomic sets) + finalize ============
__global__ __launch_bounds__(256) void k_bn_final(const float* __restrict__ sets,
                                                  const float* __restrict__ g, const float* __restrict__ b,
                                                  float* __restrict__ scsh, int N){
  __shared__ float sm[256];
  int t = threadIdx.x;
  sm[t] = reduce_part(sets, 64, t);
  __syncthreads();
  if (t < 128){
    float mean = sm[t] / (float)N;
    float var  = sm[128+t] / (float)N - mean*mean;
    float rstd = rsqrtf(var + EPSV);
    float sc = g[t] * rstd;
    scsh[t] = sc; scsh[128+t] = b[t] - mean*sc;
  }
}

// ============ fused top-scan + down-sweep ============
__global__ __launch_bounds__(256) void k_scan_down2(const int* __restrict__ in, const int* __restrict__ bsum,
                                                    int nb, int* __restrict__ outp,
                                                    int* __restrict__ rowptr, int len, int N, int E){
  __shared__ int ls[256], top[256];
  int t = threadIdx.x, b = blockIdx.x;
  int tv = (t < nb) ? bsum[t] : 0;
  top[t] = tv; __syncthreads();
  for (int off = 1; off < 256; off <<= 1){
    int add = (t >= off) ? top[t - off] : 0;
    __syncthreads();
    top[t] += add;
    __syncthreads();
  }
  int base = (b > 0) ? top[b - 1] : 0;
  int i = b*256 + t;
  int v = (i < len) ? in[i] : 0;
  ls[t] = v; __syncthreads();
  for (int off = 1; off < 256; off <<= 1){
    int add = (t >= off) ? ls[t - off] : 0;
    __syncthreads();
    ls[t] += add;
    __syncthreads();
  }
  if (i < len) outp[i] = ls[t] - v + base;
  if (b == 0 && t == 0) rowptr[N] = E;
}

// ============ fine sort within bucket (1024 threads): rowptr + csr_src (LDS atomics only) ============
__global__ __launch_bounds__(1024) void k_finesort(const int2* __restrict__ ebuf, const int* __restrict__ scn,
                                                   int* __restrict__ rowptr, int* __restrict__ csr_src,
                                                   int B, int C, int N, int E){
  __shared__ int ls[256], cur[256];
  int b = blockIdx.x, t = threadIdx.x;
  int base = scn[b*C];
  int end  = (b == B-1) ? E : scn[(b+1)*C];
  int lo = b << 8;
  if (t < 256) cur[t] = 0;
  __syncthreads();
  for (int e = base + t; e < end; e += 1024) atomicAdd(&cur[ebuf[e].x - lo], 1);
  __syncthreads();
  int cnt_t = 0;
  if (t < 256){ cnt_t = cur[t]; ls[t] = cnt_t; }
  __syncthreads();
  for (int off = 1; off < 256; off <<= 1){
    int add = 0;
    if (t < 256 && t >= off) add = ls[t - off];
    __syncthreads();
    if (t < 256) ls[t] += add;
    __syncthreads();
  }
  int excl_t = 0;
  if (t < 256){
    excl_t = ls[t] - cnt_t;
    if (lo + t < N) rowptr[lo + t] = base + excl_t;
  }
  __syncthreads();
  if (t < 256) cur[t] = excl_t;
  __syncthreads();
  for (int e = base + t; e < end; e += 1024){
    int2 p = ebuf[e];
    int slot = base + atomicAdd(&cur[p.x - lo], 1);
    csr_src[slot] = p.y;
  }
}

// ============ merged: bucket pass (first C blocks) + BN1-apply + QKV projection (MFMA, 32-row tiles) ============
__global__ __launch_bounds__(256) void k_qkv_bucket(
    const float* __restrict__ h, const float* __restrict__ scsh,
    const u16* __restrict__ WTq, const u16* __restrict__ WTk, const u16* __restrict__ WTv,
    u16* __restrict__ Q, u16* __restrict__ K, u16* __restrict__ V, int N,
    const int* __restrict__ src, const int* __restrict__ dst,
    const int* __restrict__ scn, int2* __restrict__ ebuf, int B, int C, int E){
  __shared__ u16 hn[32][136];
  __shared__ u16 ob[32][136];
  __shared__ int off[256];
  int b = blockIdx.x, t = threadIdx.x;
  if (b < C){
    off[t] = (t < B) ? scn[t*C + b] : 0;
    __syncthreads();
    int e0 = b * 4096;
    #pragma unroll
    for (int j = 0; j < 16; j++){
      int e = e0 + t + j*256;
      if (e < E){
        int d = dst[e], s = src[e];
        int slot = atomicAdd(&off[d >> 8], 1);
        ebuf[slot] = make_int2(d, s);
      }
    }
    return;
  }
  int r0 = (b - C) * 32;
  int row = t >> 3, c0 = (t & 7) * 16;
  {
    int rr = r0 + row;
    #pragma unroll
    for (int j = 0; j < 4; j++){
      int c = c0 + 4*j;
      float4 v = make_float4(0.f,0.f,0.f,0.f);
      if (rr < N) v = *(const float4*)(h + (size_t)rr*NDIM + c);
      us4 o;
      o.x = f2b(v.x * scsh[c]   + scsh[128+c]);
      o.y = f2b(v.y * scsh[c+1] + scsh[129+c]);
      o.z = f2b(v.z * scsh[c+2] + scsh[130+c]);
      o.w = f2b(v.w * scsh[c+3] + scsh[131+c]);
      *(us4*)&hn[row][c] = o;
    }
  }
  __syncthreads();
  int lane = t & 63, w = t >> 6;
  int lr = lane & 15, kg = lane >> 4;
  f32x4 zero = {0.f,0.f,0.f,0.f};

  #define DO_PASS(WT, OUT, FIRST) { \
    f32x4 acc[2][2]; \
    _Pragma("unroll") for (int n = 0; n < 2; n++) _Pragma("unroll") for (int m = 0; m < 2; m++) acc[n][m] = zero; \
    gemm_tiles<2,2,4,128,136>(&hn[0][0], WT, lr, kg, w*32, acc); \
    if (!FIRST) __syncthreads(); \
    _Pragma("unroll") for (int n = 0; n < 2; n++){ \
      int col = w*32 + n*16 + lr; \
      _Pragma("unroll") for (int m = 0; m < 2; m++) \
        _Pragma("unroll") for (int r = 0; r < 4; r++) \
          ob[m*16 + kg*4 + r][col] = f2b(acc[n][m][r]); \
    } \
    __syncthreads(); \
    if (r0 + row < N){ \
      u16* dp = OUT + (size_t)(r0 + row)*NDIM + c0; \
      *(us8*)dp       = *(const us8*)&ob[row][c0]; \
      *(us8*)(dp + 8) = *(const us8*)&ob[row][c0 + 8]; \
    } }

  DO_PASS(WTq, Q, true)

  // K pass: GEMM -> ob(bf16) -> fp8 (or bf16 fallback) coalesced store
  {
    f32x4 acc[2][2];
    #pragma unroll
    for (int n = 0; n < 2; n++)
      #pragma unroll
      for (int m = 0; m < 2; m++) acc[n][m] = zero;
    gemm_tiles<2,2,4,128,136>(&hn[0][0], WTk, lr, kg, w*32, acc);
    __syncthreads();
    #pragma unroll
    for (int n = 0; n < 2; n++){
      int col = w*32 + n*16 + lr;
      #pragma unroll
      for (int m = 0; m < 2; m++)
        #pragma unroll
        for (int r = 0; r < 4; r++)
          ob[m*16 + kg*4 + r][col] = f2b(acc[n][m][r]);
    }
    __syncthreads();
    if (r0 + row < N){
#if HAVE_FP8
      u8* dp = (u8*)K + (size_t)(r0 + row)*NDIM + c0;
      unsigned wd[4];
      #pragma unroll
      for (int j = 0; j < 2; j++){
        us8 v = *(const us8*)&ob[row][c0 + 8*j];
        int w0 = __builtin_amdgcn_cvt_pk_fp8_f32(b2f(v[0]), b2f(v[1]), 0, false);
        w0     = __builtin_amdgcn_cvt_pk_fp8_f32(b2f(v[2]), b2f(v[3]), w0, true);
        int w1 = __builtin_amdgcn_cvt_pk_fp8_f32(b2f(v[4]), b2f(v[5]), 0, false);
        w1     = __builtin_amdgcn_cvt_pk_fp8_f32(b2f(v[6]), b2f(v[7]), w1, true);
        wd[2*j] = (unsigned)w0; wd[2*j+1] = (unsigned)w1;
      }
      *(uint4*)dp = make_uint4(wd[0], wd[1], wd[2], wd[3]);
#else
      u16* dp = K + (size_t)(r0 + row)*NDIM + c0;
      *(us8*)dp       = *(const us8*)&ob[row][c0];
      *(us8*)(dp + 8) = *(const us8*)&ob[row][c0 + 8];
#endif
    }
  }

  DO_PASS(WTv, V, false)
  #undef DO_PASS
}

// ============ fused edge phase: score + softmax + weighted V aggregation ============
// Depth-2 software pipeline; fp8 K gather (128 B/edge); bf16 V gather (256 B/edge).
__global__ __launch_bounds__(256) void k_sagg(const int* __restrict__ rowptr, const int* __restrict__ csr_src,
                                              const u16* __restrict__ Q, const u16* __restrict__ K,
                                              const u16* __restrict__ V, u16* __restrict__ wV, int N){
  __shared__ float wx[4][64];
  int w = threadIdx.x >> 6, l = threadIdx.x & 63;
  int n = blockIdx.x*4 + w;
  if (n >= N) return;
  int j8 = l >> 3, hh = l & 7, d0 = l * 2;

  f32x2 qf[8];
  {
    const unsigned* qp = (const unsigned*)(Q + (size_t)n*NDIM + hh*16);
    #pragma unroll
    for (int t = 0; t < 8; t++){
      unsigned u = qp[t];
      qf[t].x = blo(u) * 0.25f;
      qf[t].y = bhi(u) * 0.25f;
    }
  }

  int e0 = rowptr[n], e1 = rowptr[n+1];
  int i0 = __builtin_amdgcn_readfirstlane(e0);
  int deg = e1 - e0;
  int nw  = deg >> 3;
  int rem = deg & 7;

  float ssum_l = 0.f;
  f32x2 a01 = {0.f, 0.f};

#if HAVE_FP8
  const u8* Kb = (const u8*)K;
  uint4 kA, kB;
  #define KLOAD(dst_, sidx) dst_ = *(const uint4*)(Kb + (size_t)(sidx)*NDIM + (hh << 4));
  #define KDOTP(p, kk) { \
    f32x2 p2 = {0.f, 0.f}; \
    p2 += qf[0] * __builtin_amdgcn_cvt_pk_f32_fp8((int)kk.x, false); \
    p2 += qf[1] * __builtin_amdgcn_cvt_pk_f32_fp8((int)kk.x, true); \
    p2 += qf[2] * __builtin_amdgcn_cvt_pk_f32_fp8((int)kk.y, false); \
    p2 += qf[3] * __builtin_amdgcn_cvt_pk_f32_fp8((int)kk.y, true); \
    p2 += qf[4] * __builtin_amdgcn_cvt_pk_f32_fp8((int)kk.z, false); \
    p2 += qf[5] * __builtin_amdgcn_cvt_pk_f32_fp8((int)kk.z, true); \
    p2 += qf[6] * __builtin_amdgcn_cvt_pk_f32_fp8((int)kk.w, false); \
    p2 += qf[7] * __builtin_amdgcn_cvt_pk_f32_fp8((int)kk.w, true); \
    p = p2.x + p2.y; }
#else
  struct krow { uint4 lo, hi; };
  krow kA, kB;
  #define KLOAD(dst_, sidx) { \
    const uint4* kp_ = (const uint4*)(K + (size_t)(sidx)*NDIM + hh*16); \
    dst_.lo = kp_[0]; dst_.hi = kp_[1]; }
  #define KDOTP(p, kk) { \
    f32x2 p2 = {0.f, 0.f}; \
    p2 += qf[0] * b2f2(kk.lo.x); p2 += qf[1] * b2f2(kk.lo.y); \
    p2 += qf[2] * b2f2(kk.lo.z); p2 += qf[3] * b2f2(kk.lo.w); \
    p2 += qf[4] * b2f2(kk.hi.x); p2 += qf[5] * b2f2(kk.hi.y); \
    p2 += qf[6] * b2f2(kk.hi.z); p2 += qf[7] * b2f2(kk.hi.w); \
    p = p2.x + p2.y; }
#endif

  unsigned vvA[8], vvB[8];

  if (nw >= 1){
    int s0=csr_src[i0+0], s1=csr_src[i0+1], s2=csr_src[i0+2], s3=csr_src[i0+3];
    int s4=csr_src[i0+4], s5=csr_src[i0+5], s6=csr_src[i0+6], s7=csr_src[i0+7];
    vvA[0] = *(const unsigned*)(V + (size_t)s0*NDIM + d0);
    vvA[1] = *(const unsigned*)(V + (size_t)s1*NDIM + d0);
    vvA[2] = *(const unsigned*)(V + (size_t)s2*NDIM + d0);
    vvA[3] = *(const unsigned*)(V + (size_t)s3*NDIM + d0);
    vvA[4] = *(const unsigned*)(V + (size_t)s4*NDIM + d0);
    vvA[5] = *(const unsigned*)(V + (size_t)s5*NDIM + d0);
    vvA[6] = *(const unsigned*)(V + (size_t)s6*NDIM + d0);
    vvA[7] = *(const unsigned*)(V + (size_t)s7*NDIM + d0);
    int sidx = csr_src[e0 + j8];
    KLOAD(kA, sidx)
  }

  for (int wi = 0; wi < nw; wi++){
    if (wi + 1 < nw){
      int ib = i0 + wi*8 + 8;
      int s0=csr_src[ib+0], s1=csr_src[ib+1], s2=csr_src[ib+2], s3=csr_src[ib+3];
      int s4=csr_src[ib+4], s5=csr_src[ib+5], s6=csr_src[ib+6], s7=csr_src[ib+7];
      vvB[0] = *(const unsigned*)(V + (size_t)s0*NDIM + d0);
      vvB[1] = *(const unsigned*)(V + (size_t)s1*NDIM + d0);
      vvB[2] = *(const unsigned*)(V + (size_t)s2*NDIM + d0);
      vvB[3] = *(const unsigned*)(V + (size_t)s3*NDIM + d0);
      vvB[4] = *(const unsigned*)(V + (size_t)s4*NDIM + d0);
      vvB[5] = *(const unsigned*)(V + (size_t)s5*NDIM + d0);
      vvB[6] = *(const unsigned*)(V + (size_t)s6*NDIM + d0);
      vvB[7] = *(const unsigned*)(V + (size_t)s7*NDIM + d0);
      int sidx = csr_src[e0 + wi*8 + 8 + j8];
      KLOAD(kB, sidx)
    }
    float p;
    KDOTP(p, kA)
    p = fminf(5.f, fmaxf(-5.f, p));
    float wgt = __expf(p);
    ssum_l += wgt;
    wx[w][hh*8 + j8] = wgt;
    float4 wa = *(const float4*)&wx[w][j8*8];
    float4 wb = *(const float4*)&wx[w][j8*8 + 4];
    a01 += b2f2(vvA[0]) * wa.x;
    a01 += b2f2(vvA[1]) * wa.y;
    a01 += b2f2(vvA[2]) * wa.z;
    a01 += b2f2(vvA[3]) * wa.w;
    a01 += b2f2(vvA[4]) * wb.x;
    a01 += b2f2(vvA[5]) * wb.y;
    a01 += b2f2(vvA[6]) * wb.z;
    a01 += b2f2(vvA[7]) * wb.w;
    if (wi + 1 < nw){
      #pragma unroll
      for (int j = 0; j < 8; j++) vvA[j] = vvB[j];
      kA = kB;
    }
  }

  if (rem > 0){
    int i0t = i0 + nw*8;
    int s[8];
    #pragma unroll
    for (int j = 0; j < 8; j++) s[j] = csr_src[i0t + (j < rem ? j : 0)];
    unsigned vv[8];
    #pragma unroll
    for (int j = 0; j < 8; j++) vv[j] = *(const unsigned*)(V + (size_t)s[j]*NDIM + d0);
    int sidx = csr_src[i0t + (j8 < rem ? j8 : 0)];
#if HAVE_FP8
    uint4 kT;
#else
    krow kT;
#endif
    KLOAD(kT, sidx)
    float p;
    KDOTP(p, kT)
    p = fminf(5.f, fmaxf(-5.f, p));
    float wgt = (j8 < rem) ? __expf(p) : 0.f;
    ssum_l += wgt;
    wx[w][hh*8 + j8] = wgt;
    float4 wa = *(const float4*)&wx[w][j8*8];
    float4 wb = *(const float4*)&wx[w][j8*8 + 4];
    a01 += b2f2(vv[0]) * wa.x;
    a01 += b2f2(vv[1]) * wa.y;
    a01 += b2f2(vv[2]) * wa.z;
    a01 += b2f2(vv[3]) * wa.w;
    a01 += b2f2(vv[4]) * wb.x;
    a01 += b2f2(vv[5]) * wb.y;
    a01 += b2f2(vv[6]) * wb.z;
    a01 += b2f2(vv[7]) * wb.w;
  }
  #undef KLOAD
  #undef KDOTP

  ssum_l += __shfl_xor(ssum_l, 8);
  ssum_l += __shfl_xor(ssum_l, 16);
  ssum_l += __shfl_xor(ssum_l, 32);
  float ssum = __shfl(ssum_l, j8);
  float inv = (e1 > e0) ? 1.f/ssum : 0.f;
  unsigned pk = (unsigned)f2b(a01.x*inv) | (((unsigned)f2b(a01.y*inv)) << 16);
  *(unsigned*)(wV + (size_t)n*NDIM + d0) = pk;
}

// ============ O-projection + residual + BN2 partials (spread atomics, 64 sets) ============
// h-row loaded early into registers; residual added from registers (no epilogue load stall).
__global__ __launch_bounds__(256) void k_h2(const u16* __restrict__ wV, const u16* __restrict__ WTo,
                                            const float* __restrict__ bo, const float* __restrict__ h,
                                            float* __restrict__ h2, float* __restrict__ sets, int N){
  __shared__ u16 tw[32][136];
  __shared__ float ob[32][132];
  int t = threadIdx.x; int r0 = blockIdx.x * 32;
  int row = t >> 3, c0 = (t & 7) * 16;
  int rr = r0 + row;
  bool live = rr < N;
  {
    us8 z = {0,0,0,0,0,0,0,0};
    const u16* sp = wV + (size_t)rr*NDIM + c0;
    *(us8*)&tw[row][c0]     = live ? *(const us8*)sp       : z;
    *(us8*)&tw[row][c0 + 8] = live ? *(const us8*)(sp + 8) : z;
  }
  // early residual load (hides under MFMA)
  float4 hv[4];
  if (live){
    const float* hp = h + (size_t)rr*NDIM + c0;
    #pragma unroll
    for (int j = 0; j < 4; j++) hv[j] = *(const float4*)(hp + 4*j);
  } else {
    #pragma unroll
    for (int j = 0; j < 4; j++) hv[j] = make_float4(0.f,0.f,0.f,0.f);
  }
  __syncthreads();
  int lane = t & 63, w = t >> 6;
  int lr = lane & 15, kg = lane >> 4;
  f32x4 zero = {0.f,0.f,0.f,0.f};
  f32x4 acc[2][2];
  #pragma unroll
  for (int n = 0; n < 2; n++)
    #pragma unroll
    for (int m = 0; m < 2; m++) acc[n][m] = zero;
  gemm_tiles<2,2,4,128,136>(&tw[0][0], WTo, lr, kg, w*32, acc);
  #pragma unroll
  for (int n = 0; n < 2; n++){
    int col = w*32 + n*16 + lr;
    float bb = bo[col];
    #pragma unroll
    for (int m = 0; m < 2; m++)
      #pragma unroll
      for (int r = 0; r < 4; r++)
        ob[m*16 + kg*4 + r][col] = acc[n][m][r] + bb;
  }
  __syncthreads();
  if (live){
    float* op = h2 + (size_t)rr*NDIM + c0;
    #pragma unroll
    for (int j = 0; j < 4; j++){
      float4 o;
      o.x = ob[row][c0 + 4*j]     + hv[j].x;
      o.y = ob[row][c0 + 4*j + 1] + hv[j].y;
      o.z = ob[row][c0 + 4*j + 2] + hv[j].z;
      o.w = ob[row][c0 + 4*j + 3] + hv[j].w;
      *(float4*)(op + 4*j) = o;
      ob[row][c0 + 4*j]     = o.x;
      ob[row][c0 + 4*j + 1] = o.y;
      ob[row][c0 + 4*j + 2] = o.z;
      ob[row][c0 + 4*j + 3] = o.w;
    }
  } else {
    #pragma unroll
    for (int j = 0; j < 16; j++) ob[row][c0 + j] = 0.f;
  }
  __syncthreads();
  int colx = t & 127, hf = t >> 7;
  float s = 0.f, q = 0.f;
  #pragma unroll
  for (int r = 0; r < 16; r++){ float v = ob[hf*16 + r][colx]; s += v; q += v*v; }
  float* cs = (float*)&tw[0][0];
  cs[hf*256 + colx]       = s;
  cs[hf*256 + 128 + colx] = q;
  __syncthreads();
  if (t < 128){
    float* sp = sets + ((size_t)(blockIdx.x & 63) << 8);
    atomicAdd(&sp[t],       cs[t]       + cs[256 + t]);
    atomicAdd(&sp[128 + t], cs[128 + t] + cs[384 + t]);
  }
}

// ============ BN2-apply + FFN + residual (register-carried residual, no h2 re-read) ============
__global__ __launch_bounds__(256) void k_ffn(const float* __restrict__ h2, const float* __restrict__ scsh,
                                             const u16* __restrict__ WT1, const float* __restrict__ b1,
                                             const u16* __restrict__ WT2, const float* __restrict__ b2,
                                             float* __restrict__ out, int N){
  __shared__ u16 x[32][136];
  __shared__ u16 tt[32][264];          // reused as float [32][132] after GEMM2
  int t = threadIdx.x; int r0 = blockIdx.x * 32;
  int row = t >> 3, c0 = (t & 7) * 16;
  int rr = r0 + row;
  bool live = rr < N;
  float4 hv[4];                        // register-carried residual
  {
    #pragma unroll
    for (int j = 0; j < 4; j++){
      int c = c0 + 4*j;
      float4 v = make_float4(0.f,0.f,0.f,0.f);
      if (live) v = *(const float4*)(h2 + (size_t)rr*NDIM + c);
      hv[j] = v;
      us4 o;
      o.x = f2b(v.x * scsh[c]   + scsh[128+c]);
      o.y = f2b(v.y * scsh[c+1] + scsh[129+c]);
      o.z = f2b(v.z * scsh[c+2] + scsh[130+c]);
      o.w = f2b(v.w * scsh[c+3] + scsh[131+c]);
      *(us4*)&x[row][c] = o;
    }
  }
  __syncthreads();
  int lane = t & 63, w = t >> 6;
  int lr = lane & 15, kg = lane >> 4;
  f32x4 zero = {0.f,0.f,0.f,0.f};
  {
    f32x4 a1[4][2];
    #pragma unroll
    for (int n = 0; n < 4; n++)
      #pragma unroll
      for (int m = 0; m < 2; m++) a1[n][m] = zero;
    gemm_tiles<4,2,4,128,136>(&x[0][0], WT1, lr, kg, w*64, a1);
    #pragma unroll
    for (int n = 0; n < 4; n++){
      int col = w*64 + n*16 + lr;
      float bb = b1[col];
      #pragma unroll
      for (int m = 0; m < 2; m++)
        #pragma unroll
        for (int r = 0; r < 4; r++)
          tt[m*16 + kg*4 + r][col] = f2b(fmaxf(a1[n][m][r] + bb, 0.f));
    }
  }
  __syncthreads();
  f32x4 a2[2][2];
  #pragma unroll
  for (int n = 0; n < 2; n++)
    #pragma unroll
    for (int m = 0; m < 2; m++) a2[n][m] = zero;
  gemm_tiles<2,2,8,256,264>(&tt[0][0], WT2, lr, kg, w*32, a2);
  __syncthreads();
  float* ob2 = (float*)&tt[0][0];       // [32][132] overlay
  #pragma unroll
  for (int n = 0; n < 2; n++){
    int col = w*32 + n*16 + lr;
    float bb = b2[col];
    #pragma unroll
    for (int m = 0; m < 2; m++)
      #pragma unroll
      for (int r = 0; r < 4; r++)
        ob2[(m*16 + kg*4 + r)*132 + col] = a2[n][m][r] + bb;
  }
  __syncthreads();
  if (live){
    float* op = out + (size_t)rr*NDIM + c0;
    #pragma unroll
    for (int j = 0; j < 4; j++){
      float4 o;
      o.x = ob2[row*132 + c0 + 4*j]     + hv[j].x;
      o.y = ob2[row*132 + c0 + 4*j + 1] + hv[j].y;
      o.z = ob2[row*132 + c0 + 4*j + 2] + hv[j].z;
      o.w = ob2[row*132 + c0 + 4*j + 3] + hv[j].w;
      *(float4*)(op + 4*j) = o;
    }
  }
}

extern "C" void kernel_launch(void* const* d_in, const int* in_sizes, int n_in,
                              void* d_out, int out_size, void* d_ws, size_t ws_size,
                              hipStream_t stream) {
  const float* h    = (const float*)d_in[0];
  const int*   src  = (const int*)d_in[1];
  const int*   dst  = (const int*)d_in[2];
  const float* Wq   = (const float*)d_in[3];
  const float* Wk   = (const float*)d_in[4];
  const float* Wv   = (const float*)d_in[5];
  const float* Wo   = (const float*)d_in[6];
  const float* bo   = (const float*)d_in[7];
  const float* bn1g = (const float*)d_in[8];
  const float* bn1b = (const float*)d_in[9];
  const float* bn2g = (const float*)d_in[10];
  const float* bn2b = (const float*)d_in[11];
  const float* W1   = (const float*)d_in[12];
  const float* b1   = (const float*)d_in[13];
  const float* W2   = (const float*)d_in[14];
  const float* b2   = (const float*)d_in[15];
  float* out = (float*)d_out;

  int N = in_sizes[0] / NDIM;
  int E = in_sizes[1];
  size_t fN = (size_t)N * NDIM;

  int B   = (N + 255) >> 8;       // coarse buckets (256 nodes each), <= 256
  int C   = (E + 4095) >> 12;     // edge chunks (4096 edges each)
  int NB2 = B * C;
  int nb2 = (NB2 + 255) / 256;    // <= 256
  int nBn = (N + 127) / 128;
  int n32 = (N + 31) / 32;

  u16* Q  = (u16*)d_ws;
  u16* K  = Q + fN;               // fp8 path uses first fN BYTES of this 2*fN-byte slot
  u16* V  = K + fN;
  u16* wV = Q;                    // reuse: each wave reads Q[n] before writing wV[n]
  float* h2   = (float*)(V + fN);
  int2* ebuf  = (int2*)(h2 + fN);
  int* rowptr = (int*)(ebuf + E);
  int* bsum   = rowptr + (N + 1);
  int* cntT   = bsum + 256;
  int* scn    = cntT + NB2;
  int* csr_src= scn + NB2;
  float* sets1 = (float*)(csr_src + E);       // 64*256
  float* sets2 = sets1 + 64*256;              // 64*256
  float* scsh1 = sets2 + 64*256;              // 256
  float* scsh2 = scsh1 + 256;                 // 256
  u16* wtq = (u16*)(scsh2 + 256);
  u16* wtk = wtq + NDIM*NDIM;
  u16* wtv = wtk + NDIM*NDIM;
  u16* wto = wtv + NDIM*NDIM;
  u16* wt1 = wto + NDIM*NDIM;
  u16* wt2 = wt1 + NDIM*2*NDIM;

  hipMemsetAsync(sets1, 0, 2*64*256*sizeof(float), stream);

  k_pro<<<nBn + 32 + C, 256, 0, stream>>>(Wq, Wk, Wv, Wo, W1, W2,
                                          wtq, wtk, wtv, wto, wt1, wt2,
                                          h, sets1, dst, cntT, nBn, N, E, B, C);
  k_bnf_scan<<<1 + nb2, 256, 0, stream>>>(sets1, bn1g, bn1b, scsh1, N, cntT, bsum, NB2);
  k_scan_down2<<<nb2, 256, 0, stream>>>(cntT, bsum, nb2, scn, rowptr, NB2, N, E);

  k_qkv_bucket<<<C + n32, 256, 0, stream>>>(h, scsh1, wtq, wtk, wtv, Q, K, V, N,
                                            src, dst, scn, ebuf, B, C, E);
  k_finesort<<<B, 1024, 0, stream>>>(ebuf, scn, rowptr, csr_src, B, C, N, E);

  k_sagg<<<(N + 3)/4, 256, 0, stream>>>(rowptr, csr_src, Q, K, V, wV, N);

  k_h2<<<n32, 256, 0, stream>>>(wV, wto, bo, h, h2, sets2, N);
  k_bn_final<<<1, 256, 0, stream>>>(sets2, bn2g, bn2b, scsh2, N);
  k_ffn<<<n32, 256, 0, stream>>>(h2, scsh2, wt1, b1, wt2, b2, out, N);
}